// Round 15
// baseline (343.682 us; speedup 1.0000x reference)
//
#include <hip/hip_runtime.h>
#include <hip/hip_bf16.h>

#define NCN 10000   // computation nodes
#define ECN 120000  // computation edges
#define NHH 256     // hidden
#define CEE 16      // cedge feat dim
#define GCN 100     // cgroups
#define GSZ 100     // nodes per cgroup
#define NTT 16      // topo nodes
#define ETT 64      // topo edges
#define TGG 8       // tgroups
#define OPEE 4
#define CFF 64
#define TFF 32
#define TEE 16
#define HFW 272     // true K (256 + 16 eagg)
#define HFP 304     // LDS row stride (ushorts), recurrent: 288 used + pad (bank-conflict 8->4 way)
#define HFP0 112    // LDS row stride, layer-0: 96 used + pad
#define NPACKR (5*9*16*64)   // 46080 packwr items -> 180 blocks
#define NPACK0 (3*16*64)     // 3072 packw0 items  -> 12 blocks

typedef __attribute__((ext_vector_type(8))) short bf16x8;
typedef __attribute__((ext_vector_type(4))) float f32x4;

// ---------- static device scratch (no d_ws dependency) ----------
__device__ int    g_indeg[NCN];
__device__ int    g_outdeg[NCN];
__device__ int    g_cursor[NCN];
__device__ int    g_off[NCN+1];
__device__ int    g_eid[ECN];
__device__ int    g_srcarr[ECN];
__device__ float  g_onorm[NCN];
__device__ float  g_inorm[NCN];
__device__ float  g_son[NCN];
__device__ float  g_tx0[NTT*NHH];
__device__ float  g_tx1[NTT*NHH];
__device__ float  g_v0p[TGG*NHH];
__device__ float  g_v0[NHH];
__device__ float  g_x0[(size_t)NCN*NHH];     // f32 xn state (normalized) / final raw
__device__ float  g_x1[(size_t)NCN*NHH];
__device__ ushort g_xb0[(size_t)NCN*NHH];    // bf16 mirror of xn (gather input)
__device__ ushort g_xb1[(size_t)NCN*NHH];
__device__ ushort g_eaT [NCN*CEE];           // bf16 eagg  (recurrent tail, layer-invariant)
__device__ ushort g_eaRT[NCN*CEE];           // bf16 eaggR (layer-0 tail)
__device__ ushort g_wpk [NPACKR*8];          // cWr packed into B-fragment order
__device__ ushort g_wpk0[NPACK0*8];          // cW0 packed (k=68..71 zeroed; v0 term in f32 epilogue)
__device__ float  g_cembp[4*GCN*NHH];

__device__ __forceinline__ int clampi(int v,int lo,int hi){ return v<lo?lo:(v>hi?hi:v); }
__device__ __forceinline__ ushort f2bu(float f){ __hip_bfloat16 h=__float2bfloat16(f); return *reinterpret_cast<ushort*>(&h); }
__device__ __forceinline__ float  bu2f(ushort u){ return __uint_as_float(((unsigned)u)<<16); }

__global__ __launch_bounds__(256) void k_badsize(float* out, int n, float code){
    int i = blockIdx.x*256 + threadIdx.x;
    if (i < n) out[i] = code;
}

// ---------------- prep0: packwr (blocks 0..179) | packw0 (180..191) | zero (192..231) ----------------
__global__ __launch_bounds__(256) void k_prep0(const float* __restrict__ cWr, const float* __restrict__ cW0){
    int bid = blockIdx.x, t = threadIdx.x;
    if (bid < 180){
        int i = bid*256 + t;
        if (i >= NPACKR) return;
        int lane = i&63, u = i>>6;
        int ntg = u&15; u >>= 4;
        int kt = u%9, l = u/9;
        int col = ntg*16 + (lane&15);
        int kb = kt*32 + 8*(lane>>4);
        #pragma unroll
        for (int j=0;j<8;j++){
            int k = kb + j;
            float v = (k < HFW) ? cWr[(size_t)l*HFW*NHH + (size_t)k*NHH + col] : 0.f;
            g_wpk[(size_t)i*8 + j] = f2bu(v);
        }
    } else if (bid < 192){
        int i = (bid-180)*256 + t;
        if (i >= NPACK0) return;
        int lane = i&63, u = i>>6;
        int ntg = u&15, kt = u>>4;
        int col = ntg*16 + (lane&15);
        int kb = kt*32 + 8*(lane>>4);
        #pragma unroll
        for (int j=0;j<8;j++){
            int k = kb + j;
            float v = 0.f;
            if (k < CFF+OPEE)            v = cW0[(size_t)k*NHH+col];
            else if (k >= 72 && k < 88)  v = cW0[(size_t)(CFF+OPEE+TGG*NHH + (k-72))*NHH + col];
            g_wpk0[(size_t)i*8 + j] = f2bu(v);
        }
    } else {
        int i = (bid-192)*256 + t;
        if (i < NCN){ g_indeg[i]=0; g_outdeg[i]=0; g_cursor[i]=0; }
    }
}

// ---------------- graph prep ----------------
__global__ __launch_bounds__(256) void k_degrees(const int* __restrict__ src, const int* __restrict__ dst){
    int e = blockIdx.x*256 + threadIdx.x;
    if (e < ECN){
        atomicAdd(&g_outdeg[clampi(src[e],0,NCN-1)],1);
        atomicAdd(&g_indeg [clampi(dst[e],0,NCN-1)],1);
    }
}

// exclusive scan of indeg -> off[0..NCN]; fused degree norms
__global__ __launch_bounds__(1024) void k_scan(){
    __shared__ int cs[1024];
    const int CH = (NCN + 1023)/1024;
    int t = threadIdx.x;
    int base = t*CH;
    for (int j=0;j<CH;j++){
        int idx = base+j;
        if (idx < NCN){
            g_onorm[idx] = rsqrtf((float)max(g_outdeg[idx],1));
            g_inorm[idx] = rsqrtf((float)max(g_indeg[idx],1));
        }
    }
    int s = 0;
    for (int j=0;j<CH;j++){ int idx=base+j; if (idx<NCN) s += g_indeg[idx]; }
    cs[t] = s; __syncthreads();
    for (int ofs=1; ofs<1024; ofs<<=1){
        int v = (t>=ofs) ? cs[t-ofs] : 0;
        __syncthreads();
        cs[t] += v;
        __syncthreads();
    }
    int run = (t==0) ? 0 : cs[t-1];
    for (int j=0;j<CH;j++){
        int idx = base+j;
        if (idx <= NCN) g_off[idx] = run;
        if (idx < NCN) run += g_indeg[idx];
    }
}

__global__ __launch_bounds__(256) void k_scatter(const int* __restrict__ dst){
    int e = blockIdx.x*256 + threadIdx.x;
    if (e < ECN){
        int d = clampi(dst[e],0,NCN-1);
        int pos = g_off[d] + atomicAdd(&g_cursor[d],1);
        g_eid[clampi(pos,0,ECN-1)] = e;
    }
}

// wave-per-node bitonic sort of eid + srcarr fill + fused edge-feature aggregation
__global__ __launch_bounds__(256) void k_sortfill(const int* __restrict__ c_src, const float* __restrict__ ef){
    const int wv = threadIdx.x >> 6, lane = threadIdx.x & 63;
    const int d = blockIdx.x*4 + wv;
    int b = clampi(g_off[d],0,ECN), e = clampi(g_off[d+1],b,ECN);
    int deg = e - b;
    if (deg <= 64){
        int v = (lane < deg) ? g_eid[b+lane] : 0x7fffffff;
        #pragma unroll
        for (int k=2;k<=64;k<<=1){
            #pragma unroll
            for (int j=k>>1;j>0;j>>=1){
                int p = __shfl_xor(v, j, 64);
                bool takeMin = ((lane & j)==0) == ((lane & k)==0);
                v = takeMin ? min(v,p) : max(v,p);
            }
        }
        if (lane < deg){
            g_eid[b+lane] = v;
            g_srcarr[b+lane] = clampi(c_src[clampi(v,0,ECN-1)],0,NCN-1);
        }
        float s=0.f, sr=0.f;
        for (int i=0;i<deg;i++){
            int ei = __shfl(v, i&63);
            if (lane < CEE){
                float val = ef[(size_t)clampi(ei,0,ECN-1)*CEE + lane];
                s += val; sr += fmaxf(val,0.f);
            }
        }
        if (lane < CEE){
            g_eaT [d*CEE+lane] = f2bu(s);
            g_eaRT[d*CEE+lane] = f2bu(sr);
        }
    } else if (lane == 0){
        for (int i=b+1;i<e;i++){
            int key = g_eid[i]; int j = i-1;
            while (j>=b && g_eid[j]>key){ g_eid[j+1]=g_eid[j]; j--; }
            g_eid[j+1] = key;
        }
        for (int i=b;i<e;i++) g_srcarr[i] = clampi(c_src[clampi(g_eid[i],0,ECN-1)],0,NCN-1);
        for (int f=0;f<CEE;f++){
            float s=0.f, sr=0.f;
            for (int i=b;i<e;i++){
                float val = ef[(size_t)clampi(g_eid[i],0,ECN-1)*CEE + f];
                s += val; sr += fmaxf(val,0.f);
            }
            g_eaT [d*CEE+f] = f2bu(s);
            g_eaRT[d*CEE+f] = f2bu(sr);
        }
    }
}

// ---- topo helpers ----
__device__ __forceinline__ void topo_edges_norms(
    const int* __restrict__ t_src, const int* __restrict__ t_dst,
    int* ssrc, int* sdst, int* sdeg, float* onrm, float* inrm, int t)
{
    if (t < 2*NTT) sdeg[t]=0;
    __syncthreads();
    if (t < ETT){
        int s=clampi(t_src[t],0,NTT-1), d=clampi(t_dst[t],0,NTT-1);
        ssrc[t]=s; sdst[t]=d;
        atomicAdd(&sdeg[s],1); atomicAdd(&sdeg[NTT+d],1);
    }
    __syncthreads();
    if (t < NTT){
        onrm[t]=rsqrtf((float)max(sdeg[t],1));
        inrm[t]=rsqrtf((float)max(sdeg[NTT+t],1));
    }
    __syncthreads();
}

__global__ __launch_bounds__(256) void kt_l0(
    const float* __restrict__ tfeats, const float* __restrict__ tef,
    const float* __restrict__ tW0, const float* __restrict__ tb0,
    const int* __restrict__ t_src, const int* __restrict__ t_dst)
{
    __shared__ float h[48];
    __shared__ int ssrc[ETT], sdst[ETT], sdeg[2*NTT];
    __shared__ float onrm[NTT], inrm[NTT];
    const int d = blockIdx.x, t = threadIdx.x;
    topo_edges_norms(t_src, t_dst, ssrc, sdst, sdeg, onrm, inrm, t);
    if (t < 48){
        float acc=0.f;
        for (int e=0;e<ETT;e++){
            if (sdst[e]==d){
                int s=ssrc[e];
                float v = (t<TFF) ? tfeats[s*TFF+t]*onrm[s] : tef[e*TEE+(t-TFF)];
                acc += fmaxf(v,0.f);
            }
        }
        h[t]=acc;
    }
    __syncthreads();
    float acc=0.f;
    for (int k=0;k<48;k++) acc += h[k]*tW0[k*NHH+t];
    g_tx0[d*NHH+t] = fmaxf(acc*inrm[d]+tb0[t], 0.f);
}

template<int DIR>
__global__ __launch_bounds__(256) void kt_lr(
    const float* __restrict__ tef,
    const float* __restrict__ W, const float* __restrict__ bias,
    const int* __restrict__ t_src, const int* __restrict__ t_dst, int relu_res)
{
    const float* xin  = DIR ? g_tx1 : g_tx0;
    float*       xout = DIR ? g_tx0 : g_tx1;
    __shared__ float h[NHH+TEE];
    __shared__ int ssrc[ETT], sdst[ETT], sdeg[2*NTT];
    __shared__ float onrm[NTT], inrm[NTT];
    const int d = blockIdx.x, t = threadIdx.x;
    topo_edges_norms(t_src, t_dst, ssrc, sdst, sdeg, onrm, inrm, t);
    {
        float a0=0.f, a1=0.f;
        for (int e=0;e<ETT;e++){
            if (sdst[e]==d){
                a0 += xin[ssrc[e]*NHH+t]*onrm[ssrc[e]];
                if (t<TEE) a1 += tef[e*TEE+t];
            }
        }
        h[t]=a0;
        if (t<TEE) h[NHH+t]=a1;
    }
    __syncthreads();
    float acc=0.f;
    for (int k=0;k<NHH+TEE;k++) acc += h[k]*W[(size_t)k*NHH+t];
    float val = acc*inrm[d] + bias[t];
    xout[d*NHH+t] = relu_res ? (xin[d*NHH+t]*onrm[d] + fmaxf(val,0.f)) : val;
}

__global__ __launch_bounds__(256) void k_v0(const float* __restrict__ cW0, const int* __restrict__ tgroups){
    __shared__ float srt[NHH];
    int b=blockIdx.x, c=threadIdx.x;
    int i0=clampi(tgroups[b*2+0],0,NTT-1), i1=clampi(tgroups[b*2+1],0,NTT-1);
    srt[c]=fmaxf(g_tx1[i0*NHH+c]+g_tx1[i1*NHH+c],0.f);
    __syncthreads();
    const float* Wm = cW0 + (size_t)(CFF+OPEE + b*NHH)*NHH;
    float acc=0.f;
    for (int j=0;j<NHH;j++) acc += srt[j]*Wm[(size_t)j*NHH+c];
    g_v0p[b*NHH+c]=acc;
}
__global__ __launch_bounds__(256) void k_v0r(){
    int c=threadIdx.x;
    float s=0.f;
    for (int b=0;b<TGG;b++) s+=g_v0p[b*NHH+c];
    g_v0[c]=s;
}

// ---------- fused layer-0: gather (4 waves x 4 nodes -> LDS) + MFMA + epilogue ----------
__global__ __launch_bounds__(256) void k_fl0(
    const int* __restrict__ ctypes,
    const float* __restrict__ cfeats, const float* __restrict__ opemb,
    const float* __restrict__ cb0)
{
    __shared__ ushort sA[16*HFP0];
    __shared__ float  sSon[16];
    const int d0 = blockIdx.x*16;
    const int w = threadIdx.x>>6, l = threadIdx.x&63;

    #pragma unroll
    for (int nn=0; nn<4; ++nn){
        int n = w*4+nn, d = d0+n;
        int b = g_off[d], e = g_off[d+1];
        int deg = e - b;
        int sv = 0; float onv = 0.f; int ctv = 0;
        if (l < deg){
            int s = g_srcarr[b+l];
            sv = s; onv = g_onorm[s]; ctv = clampi(ctypes[s],0,255);
        }
        float a_cf=0.f, a_op=0.f, aon=0.f;
        for (int i=0;i<deg;i++){
            int s; float on; int ct;
            if (i < 64){ s = __shfl(sv,i&63); on = __shfl(onv,i&63); ct = __shfl(ctv,i&63); }
            else { s = g_srcarr[b+i]; on = g_onorm[s]; ct = clampi(ctypes[s],0,255); }
            a_cf += fmaxf(cfeats[(size_t)s*CFF+l],0.f)*on;
            if (l < OPEE) a_op += fmaxf(opemb[ct*OPEE+l],0.f)*on;
            aon += on;
        }
        ushort* row = sA + n*HFP0;
        row[l] = f2bu(a_cf);
        if (l < OPEE)            row[CFF+l] = f2bu(a_op);
        if (l >= 4 && l < 8)     row[64+l] = 0;           // cols 68..71
        if (l >= 8 && l < 16)    row[80+l] = 0;           // cols 88..95
        if (l == 16)             sSon[n] = aon;
    }
    {   // eaggR tail cols 72..87
        int n = threadIdx.x>>4, f = threadIdx.x&15;
        sA[n*HFP0 + 72 + f] = g_eaRT[(d0+n)*CEE + f];
    }
    __syncthreads();

    const ushort* arow = sA + (l&15)*HFP0 + 8*(l>>4);
    f32x4 acc0={0,0,0,0}, acc1={0,0,0,0}, acc2={0,0,0,0}, acc3={0,0,0,0};
    for (int kt=0; kt<3; kt++){
        bf16x8 a = *(const bf16x8*)(arow + kt*32);
        const ushort* bp = g_wpk0 + ((size_t)((kt*16 + w*4)*64 + l))*8;
        bf16x8 b0 = *(const bf16x8*)(bp);
        bf16x8 b1 = *(const bf16x8*)(bp + 64*8);
        bf16x8 b2 = *(const bf16x8*)(bp + 2*64*8);
        bf16x8 b3 = *(const bf16x8*)(bp + 3*64*8);
        acc0 = __builtin_amdgcn_mfma_f32_16x16x32_bf16(a, b0, acc0, 0,0,0);
        acc1 = __builtin_amdgcn_mfma_f32_16x16x32_bf16(a, b1, acc1, 0,0,0);
        acc2 = __builtin_amdgcn_mfma_f32_16x16x32_bf16(a, b2, acc2, 0,0,0);
        acc3 = __builtin_amdgcn_mfma_f32_16x16x32_bf16(a, b3, acc3, 0,0,0);
    }
    const int rb = (l>>4)*4, cb = w*64 + (l&15);
    #define EPI0(ACC, NT) { \
        int col = cb + (NT)*16; float bb = cb0[col]; float v0c = g_v0[col]; \
        _Pragma("unroll") for (int r=0;r<4;r++){ \
            int d = d0 + rb + r; \
            float val = (ACC[r] + sSon[rb+r]*v0c)*g_inorm[d] + bb; \
            float xn = fmaxf(val,0.f)*g_onorm[d]; \
            g_x0 [(size_t)d*NHH+col] = xn; \
            g_xb0[(size_t)d*NHH+col] = f2bu(xn); } }
    EPI0(acc0,0) EPI0(acc1,1) EPI0(acc2,2) EPI0(acc3,3)
    #undef EPI0
}

// ---------- fused recurrent layer: gather -> LDS + MFMA + epilogue ----------
template<int DIR>   // DIR=0: in x0/xb0 -> out x1/xb1; DIR=1: reverse
__global__ __launch_bounds__(256) void k_flayer(
    int loff, const float* __restrict__ bias, int relu_res)
{
    const ushort* xb   = DIR ? g_xb1 : g_xb0;
    const float*  xnin = DIR ? g_x1  : g_x0;
    float*        xout = DIR ? g_x0  : g_x1;
    ushort*       xbout= DIR ? g_xb0 : g_xb1;
    __shared__ ushort sA[16*HFP];
    const int d0 = blockIdx.x*16;
    const int w = threadIdx.x>>6, l = threadIdx.x&63;

    #pragma unroll
    for (int nn=0; nn<4; ++nn){
        int n = w*4+nn, d = d0+n;
        int b = g_off[d], e = g_off[d+1];
        int deg = e - b;
        int sv = (l < deg) ? g_srcarr[b+l] : 0;
        float a0=0.f,a1=0.f,a2=0.f,a3=0.f;
        for (int i=0;i<deg;i++){
            int s = (i < 64) ? __shfl(sv,i&63) : g_srcarr[b+i];
            ushort4 v = *(const ushort4*)(xb + (size_t)s*NHH + 4*l);
            a0 += bu2f(v.x); a1 += bu2f(v.y); a2 += bu2f(v.z); a3 += bu2f(v.w);
        }
        ushort4 o;
        o.x=f2bu(a0); o.y=f2bu(a1); o.z=f2bu(a2); o.w=f2bu(a3);
        *(ushort4*)(sA + n*HFP + 4*l) = o;
    }
    {   // eagg tail cols 256..271 + zero pad 272..287
        int n = threadIdx.x>>4, f = threadIdx.x&15;
        sA[n*HFP + NHH + f]      = g_eaT[(d0+n)*CEE + f];
        sA[n*HFP + NHH + 16 + f] = 0;
    }
    __syncthreads();

    const ushort* arow = sA + (l&15)*HFP + 8*(l>>4);
    f32x4 acc0={0,0,0,0}, acc1={0,0,0,0}, acc2={0,0,0,0}, acc3={0,0,0,0};
    for (int kt=0; kt<9; kt++){
        bf16x8 a = *(const bf16x8*)(arow + kt*32);
        const ushort* bp = g_wpk + ((size_t)(((loff+kt)*16 + w*4)*64 + l))*8;
        bf16x8 b0 = *(const bf16x8*)(bp);
        bf16x8 b1 = *(const bf16x8*)(bp + 64*8);
        bf16x8 b2 = *(const bf16x8*)(bp + 2*64*8);
        bf16x8 b3 = *(const bf16x8*)(bp + 3*64*8);
        acc0 = __builtin_amdgcn_mfma_f32_16x16x32_bf16(a, b0, acc0, 0,0,0);
        acc1 = __builtin_amdgcn_mfma_f32_16x16x32_bf16(a, b1, acc1, 0,0,0);
        acc2 = __builtin_amdgcn_mfma_f32_16x16x32_bf16(a, b2, acc2, 0,0,0);
        acc3 = __builtin_amdgcn_mfma_f32_16x16x32_bf16(a, b3, acc3, 0,0,0);
    }
    const int rb = (l>>4)*4, cb = w*64 + (l&15);
    #define EPIR(ACC, NT) { \
        int col = cb + (NT)*16; float bb = bias[col]; \
        _Pragma("unroll") for (int r=0;r<4;r++){ \
            int d = d0 + rb + r; \
            float val = ACC[r]*g_inorm[d] + bb; \
            if (relu_res){ \
                float y = xnin[(size_t)d*NHH+col] + fmaxf(val,0.f); \
                float yn = y*g_onorm[d]; \
                xout [(size_t)d*NHH+col] = yn; \
                xbout[(size_t)d*NHH+col] = f2bu(yn); \
            } else { \
                xout[(size_t)d*NHH+col] = val; \
            } } }
    EPIR(acc0,0) EPIR(acc1,1) EPIR(acc2,2) EPIR(acc3,3)
    #undef EPIR
}

// ---------------- pooling (4 deterministic partials) + heads ----------------
__global__ __launch_bounds__(256) void k_cemb(const int* __restrict__ cgroups){
    int g=blockIdx.x>>2, p=blockIdx.x&3, c=threadIdx.x;
    float s=0.f;
    for (int i=p*25;i<p*25+25;i++){
        int idx=clampi(cgroups[g*GSZ+i],0,NCN-1);
        s += g_x1[(size_t)idx*NHH+c];
    }
    g_cembp[(size_t)(p*GCN+g)*NHH+c]=s;
}

__global__ __launch_bounds__(256) void k_heads(
    const float* __restrict__ sW, const float* __restrict__ sb,
    const float* __restrict__ nW, const float* __restrict__ nb, float* __restrict__ out)
{
    __shared__ float red[256];
    __shared__ float z[9];
    int g=blockIdx.x, t=threadIdx.x;
    float e = g_cembp[(size_t)(0*GCN+g)*NHH+t] + g_cembp[(size_t)(1*GCN+g)*NHH+t]
            + g_cembp[(size_t)(2*GCN+g)*NHH+t] + g_cembp[(size_t)(3*GCN+g)*NHH+t];
    for (int j=0;j<9;j++){
        float w = (j==0) ? nW[t] : sW[t*TGG+(j-1)];
        red[t]=e*w; __syncthreads();
        for (int s=128;s>0;s>>=1){ if (t<s) red[t]+=red[t+s]; __syncthreads(); }
        if (t==0) z[j]=red[0];
        __syncthreads();
    }
    if (t==0){
        float z0 = z[0] + nb[0];
        float lsig = fminf(z0,0.f) - log1pf(expf(-fabsf(z0)));
        out[g*9+0]=lsig;
        float zz[8]; float m=-1e30f;
        for (int j=0;j<8;j++){ zz[j]=z[j+1]+sb[j]; m=fmaxf(m,zz[j]); }
        float s=0.f;
        for (int j=0;j<8;j++) s+=expf(zz[j]-m);
        float lse=m+logf(s);
        for (int j=0;j<8;j++) out[g*9+1+j]=zz[j]-lse;
    }
}

extern "C" void kernel_launch(void* const* d_in, const int* in_sizes, int n_in,
                              void* d_out, int out_size, void* d_ws, size_t ws_size,
                              hipStream_t stream) {
    const int expect[24] = {
        NCN*CFF, ECN*CEE, NTT*TFF, ETT*TEE, 256*OPEE,
        (TFF+TEE)*NHH, NHH, 3*(NHH+TEE)*NHH, 3*NHH,
        (CFF+OPEE+TGG*NHH+CEE)*NHH, NHH, 5*(NHH+CEE)*NHH, 5*NHH,
        NHH*TGG, TGG, NHH, 1,
        NCN, ECN, ECN, ETT, ETT, GCN*GSZ, TGG*2
    };
    if (n_in < 24){
        k_badsize<<<(out_size+255)/256,256,0,stream>>>((float*)d_out, out_size, 2.0e6f);
        return;
    }
    for (int i=0;i<24;i++){
        if (in_sizes[i] != expect[i]){
            k_badsize<<<(out_size+255)/256,256,0,stream>>>((float*)d_out, out_size, 1.0e6f+(float)i);
            return;
        }
    }

    const float* cfeats = (const float*)d_in[0];
    const float* cef    = (const float*)d_in[1];
    const float* tfeats = (const float*)d_in[2];
    const float* tef    = (const float*)d_in[3];
    const float* opemb  = (const float*)d_in[4];
    const float* tW0    = (const float*)d_in[5];
    const float* tb0    = (const float*)d_in[6];
    const float* tWr    = (const float*)d_in[7];
    const float* tbr    = (const float*)d_in[8];
    const float* cW0    = (const float*)d_in[9];
    const float* cb0    = (const float*)d_in[10];
    const float* cWr    = (const float*)d_in[11];
    const float* cbr    = (const float*)d_in[12];
    const float* sW     = (const float*)d_in[13];
    const float* sb     = (const float*)d_in[14];
    const float* nW     = (const float*)d_in[15];
    const float* nb     = (const float*)d_in[16];
    const int* ctypes   = (const int*)d_in[17];
    const int* c_src    = (const int*)d_in[18];
    const int* c_dst    = (const int*)d_in[19];
    const int* t_src    = (const int*)d_in[20];
    const int* t_dst    = (const int*)d_in[21];
    const int* cgroups  = (const int*)d_in[22];
    const int* tgroups  = (const int*)d_in[23];

    const int EB = (ECN+255)/256;

    k_prep0   <<<232, 256, 0, stream>>>(cWr, cW0);
    k_degrees <<<EB, 256, 0, stream>>>(c_src, c_dst);
    k_scan    <<<1, 1024, 0, stream>>>();
    k_scatter <<<EB, 256, 0, stream>>>(c_dst);
    k_sortfill<<<NCN/4, 256, 0, stream>>>(c_src, cef);

    // topo GNN (f32)
    kt_l0    <<<NTT, 256, 0, stream>>>(tfeats, tef, tW0, tb0, t_src, t_dst);
    kt_lr<0> <<<NTT, 256, 0, stream>>>(tef, tWr + (size_t)0*(NHH+TEE)*NHH, tbr + 0*NHH, t_src, t_dst, 1);
    kt_lr<1> <<<NTT, 256, 0, stream>>>(tef, tWr + (size_t)1*(NHH+TEE)*NHH, tbr + 1*NHH, t_src, t_dst, 1);
    kt_lr<0> <<<NTT, 256, 0, stream>>>(tef, tWr + (size_t)2*(NHH+TEE)*NHH, tbr + 2*NHH, t_src, t_dst, 0);
    k_v0     <<<TGG, 256, 0, stream>>>(cW0, tgroups);
    k_v0r    <<<1, 256, 0, stream>>>();

    // cGNN: fused layers
    k_fl0       <<<NCN/16, 256, 0, stream>>>(ctypes, cfeats, opemb, cb0);
    k_flayer<0> <<<NCN/16, 256, 0, stream>>>(0*9, cbr + 0*NHH, 1);
    k_flayer<1> <<<NCN/16, 256, 0, stream>>>(1*9, cbr + 1*NHH, 1);
    k_flayer<0> <<<NCN/16, 256, 0, stream>>>(2*9, cbr + 2*NHH, 1);
    k_flayer<1> <<<NCN/16, 256, 0, stream>>>(3*9, cbr + 3*NHH, 1);
    k_flayer<0> <<<NCN/16, 256, 0, stream>>>(4*9, cbr + 4*NHH, 0);

    k_cemb <<<4*GCN, 256, 0, stream>>>(cgroups);
    k_heads<<<GCN, 256, 0, stream>>>(sW, sb, nW, nb, (float*)d_out);
}

// Round 16
// 311.747 us; speedup vs baseline: 1.1024x; 1.1024x over previous
//
#include <hip/hip_runtime.h>
#include <hip/hip_bf16.h>

#define NCN 10000   // computation nodes
#define ECN 120000  // computation edges
#define NHH 256     // hidden
#define CEE 16      // cedge feat dim
#define GCN 100     // cgroups
#define GSZ 100     // nodes per cgroup
#define NTT 16      // topo nodes
#define ETT 64      // topo edges
#define TGG 8       // tgroups
#define OPEE 4
#define CFF 64
#define TFF 32
#define TEE 16
#define HFW 272     // true K (256 + 16 eagg)
#define HFB 288     // padded K for MFMA (9*32)
#define HFB0 96     // layer-0 padded K (3*32)
#define NPACKR (5*9*16*64)   // 46080 packwr items -> 180 blocks
#define NPACK0 (3*16*64)     // 3072 packw0 items  -> 12 blocks

typedef __attribute__((ext_vector_type(8))) short bf16x8;
typedef __attribute__((ext_vector_type(4))) float f32x4;

// ---------- static device scratch (no d_ws dependency) ----------
__device__ int    g_indeg[NCN];
__device__ int    g_outdeg[NCN];
__device__ int    g_cursor[NCN];
__device__ int    g_off[NCN+1];
__device__ int    g_eid[ECN];
__device__ int    g_srcarr[ECN];
__device__ float  g_onorm[NCN];
__device__ float  g_inorm[NCN];
__device__ float  g_son[NCN];
__device__ float  g_tx0[NTT*NHH];
__device__ float  g_tx1[NTT*NHH];
__device__ float  g_v0p[TGG*NHH];
__device__ float  g_x0[(size_t)NCN*NHH];     // f32 xn state (normalized) / final raw
__device__ float  g_x1[(size_t)NCN*NHH];
__device__ ushort g_xb0[(size_t)NCN*NHH];    // bf16 mirror of xn (gather input)
__device__ ushort g_xb1[(size_t)NCN*NHH];
__device__ ushort g_hf [(size_t)NCN*HFB];    // bf16 gathered rows; [256:272]=eagg, [272:288]=0
__device__ ushort g_hf0[(size_t)NCN*HFB0];   // bf16 layer-0 rows
__device__ ushort g_wpk [NPACKR*8];          // cWr packed into B-fragment order
__device__ ushort g_wpk0[NPACK0*8];          // cW0 packed (k=68..71 zeroed; v0 term in f32 epilogue)

__device__ __forceinline__ int clampi(int v,int lo,int hi){ return v<lo?lo:(v>hi?hi:v); }
__device__ __forceinline__ ushort f2bu(float f){ __hip_bfloat16 h=__float2bfloat16(f); return *reinterpret_cast<ushort*>(&h); }
__device__ __forceinline__ float  bu2f(ushort u){ return __uint_as_float(((unsigned)u)<<16); }

__global__ __launch_bounds__(256) void k_badsize(float* out, int n, float code){
    int i = blockIdx.x*256 + threadIdx.x;
    if (i < n) out[i] = code;
}

// ---------------- prep0: packwr (blocks 0..179) | packw0 (180..191) | zero (192..231) ----------------
__global__ __launch_bounds__(256) void k_prep0(const float* __restrict__ cWr, const float* __restrict__ cW0){
    int bid = blockIdx.x, t = threadIdx.x;
    if (bid < 180){
        int i = bid*256 + t;
        if (i >= NPACKR) return;
        int lane = i&63, u = i>>6;
        int ntg = u&15; u >>= 4;
        int kt = u%9, l = u/9;
        int col = ntg*16 + (lane&15);
        int kb = kt*32 + 8*(lane>>4);
        #pragma unroll
        for (int j=0;j<8;j++){
            int k = kb + j;
            float v = (k < HFW) ? cWr[(size_t)l*HFW*NHH + (size_t)k*NHH + col] : 0.f;
            g_wpk[(size_t)i*8 + j] = f2bu(v);
        }
    } else if (bid < 192){
        int i = (bid-180)*256 + t;
        if (i >= NPACK0) return;
        int lane = i&63, u = i>>6;
        int ntg = u&15, kt = u>>4;
        int col = ntg*16 + (lane&15);
        int kb = kt*32 + 8*(lane>>4);
        #pragma unroll
        for (int j=0;j<8;j++){
            int k = kb + j;
            float v = 0.f;
            if (k < CFF+OPEE)            v = cW0[(size_t)k*NHH+col];
            else if (k >= 72 && k < 88)  v = cW0[(size_t)(CFF+OPEE+TGG*NHH + (k-72))*NHH + col];
            g_wpk0[(size_t)i*8 + j] = f2bu(v);
        }
    } else {
        int i = (bid-192)*256 + t;
        if (i < NCN){ g_indeg[i]=0; g_outdeg[i]=0; g_cursor[i]=0; }
    }
}

// ---------------- graph prep ----------------
__global__ __launch_bounds__(256) void k_degrees(const int* __restrict__ src, const int* __restrict__ dst){
    int e = blockIdx.x*256 + threadIdx.x;
    if (e < ECN){
        atomicAdd(&g_outdeg[clampi(src[e],0,NCN-1)],1);
        atomicAdd(&g_indeg [clampi(dst[e],0,NCN-1)],1);
    }
}

// exclusive scan of indeg -> off[0..NCN]; fused degree norms
__global__ __launch_bounds__(1024) void k_scan(){
    __shared__ int cs[1024];
    const int CH = (NCN + 1023)/1024;
    int t = threadIdx.x;
    int base = t*CH;
    for (int j=0;j<CH;j++){
        int idx = base+j;
        if (idx < NCN){
            g_onorm[idx] = rsqrtf((float)max(g_outdeg[idx],1));
            g_inorm[idx] = rsqrtf((float)max(g_indeg[idx],1));
        }
    }
    int s = 0;
    for (int j=0;j<CH;j++){ int idx=base+j; if (idx<NCN) s += g_indeg[idx]; }
    cs[t] = s; __syncthreads();
    for (int ofs=1; ofs<1024; ofs<<=1){
        int v = (t>=ofs) ? cs[t-ofs] : 0;
        __syncthreads();
        cs[t] += v;
        __syncthreads();
    }
    int run = (t==0) ? 0 : cs[t-1];
    for (int j=0;j<CH;j++){
        int idx = base+j;
        if (idx <= NCN) g_off[idx] = run;
        if (idx < NCN) run += g_indeg[idx];
    }
}

__global__ __launch_bounds__(256) void k_scatter(const int* __restrict__ dst){
    int e = blockIdx.x*256 + threadIdx.x;
    if (e < ECN){
        int d = clampi(dst[e],0,NCN-1);
        int pos = g_off[d] + atomicAdd(&g_cursor[d],1);
        g_eid[clampi(pos,0,ECN-1)] = e;
    }
}

// wave-per-node bitonic sort of eid + srcarr fill + fused edge-feature aggregation
__global__ __launch_bounds__(256) void k_sortfill(const int* __restrict__ c_src, const float* __restrict__ ef){
    const int wv = threadIdx.x >> 6, lane = threadIdx.x & 63;
    const int d = blockIdx.x*4 + wv;
    int b = clampi(g_off[d],0,ECN), e = clampi(g_off[d+1],b,ECN);
    int deg = e - b;
    if (deg <= 64){
        int v = (lane < deg) ? g_eid[b+lane] : 0x7fffffff;
        #pragma unroll
        for (int k=2;k<=64;k<<=1){
            #pragma unroll
            for (int j=k>>1;j>0;j>>=1){
                int p = __shfl_xor(v, j, 64);
                bool takeMin = ((lane & j)==0) == ((lane & k)==0);
                v = takeMin ? min(v,p) : max(v,p);
            }
        }
        if (lane < deg){
            g_eid[b+lane] = v;
            g_srcarr[b+lane] = clampi(c_src[clampi(v,0,ECN-1)],0,NCN-1);
        }
        float s=0.f, sr=0.f;
        for (int i=0;i<deg;i++){
            int ei = __shfl(v, i&63);
            if (lane < CEE){
                float val = ef[(size_t)clampi(ei,0,ECN-1)*CEE + lane];
                s += val; sr += fmaxf(val,0.f);
            }
        }
        if (lane < CEE){
            g_hf [(size_t)d*HFB  + NHH + lane]      = f2bu(s);
            g_hf [(size_t)d*HFB  + NHH + 16 + lane] = 0;
            g_hf0[(size_t)d*HFB0 + 72 + lane]       = f2bu(sr);
            if (lane < 8) g_hf0[(size_t)d*HFB0 + 88 + lane] = 0;
            if (lane < 4) g_hf0[(size_t)d*HFB0 + 68 + lane] = 0;
        }
    } else if (lane == 0){
        for (int i=b+1;i<e;i++){
            int key = g_eid[i]; int j = i-1;
            while (j>=b && g_eid[j]>key){ g_eid[j+1]=g_eid[j]; j--; }
            g_eid[j+1] = key;
        }
        for (int i=b;i<e;i++) g_srcarr[i] = clampi(c_src[clampi(g_eid[i],0,ECN-1)],0,NCN-1);
        for (int f=0;f<CEE;f++){
            float s=0.f, sr=0.f;
            for (int i=b;i<e;i++){
                float val = ef[(size_t)clampi(g_eid[i],0,ECN-1)*CEE + f];
                s += val; sr += fmaxf(val,0.f);
            }
            g_hf [(size_t)d*HFB  + NHH + f]      = f2bu(s);
            g_hf [(size_t)d*HFB  + NHH + 16 + f] = 0;
            g_hf0[(size_t)d*HFB0 + 72 + f]       = f2bu(sr);
            if (f < 8) g_hf0[(size_t)d*HFB0 + 88 + f] = 0;
            if (f < 4) g_hf0[(size_t)d*HFB0 + 68 + f] = 0;
        }
    }
}

// ---- topo helpers ----
__device__ __forceinline__ void topo_edges_norms(
    const int* __restrict__ t_src, const int* __restrict__ t_dst,
    int* ssrc, int* sdst, int* sdeg, float* onrm, float* inrm, int t)
{
    if (t < 2*NTT) sdeg[t]=0;
    __syncthreads();
    if (t < ETT){
        int s=clampi(t_src[t],0,NTT-1), d=clampi(t_dst[t],0,NTT-1);
        ssrc[t]=s; sdst[t]=d;
        atomicAdd(&sdeg[s],1); atomicAdd(&sdeg[NTT+d],1);
    }
    __syncthreads();
    if (t < NTT){
        onrm[t]=rsqrtf((float)max(sdeg[t],1));
        inrm[t]=rsqrtf((float)max(sdeg[NTT+t],1));
    }
    __syncthreads();
}

__global__ __launch_bounds__(256) void kt_l0(
    const float* __restrict__ tfeats, const float* __restrict__ tef,
    const float* __restrict__ tW0, const float* __restrict__ tb0,
    const int* __restrict__ t_src, const int* __restrict__ t_dst)
{
    __shared__ float h[48];
    __shared__ int ssrc[ETT], sdst[ETT], sdeg[2*NTT];
    __shared__ float onrm[NTT], inrm[NTT];
    const int d = blockIdx.x, t = threadIdx.x;
    topo_edges_norms(t_src, t_dst, ssrc, sdst, sdeg, onrm, inrm, t);
    if (t < 48){
        float acc=0.f;
        for (int e=0;e<ETT;e++){
            if (sdst[e]==d){
                int s=ssrc[e];
                float v = (t<TFF) ? tfeats[s*TFF+t]*onrm[s] : tef[e*TEE+(t-TFF)];
                acc += fmaxf(v,0.f);
            }
        }
        h[t]=acc;
    }
    __syncthreads();
    float acc=0.f;
    for (int k=0;k<48;k++) acc += h[k]*tW0[k*NHH+t];
    g_tx0[d*NHH+t] = fmaxf(acc*inrm[d]+tb0[t], 0.f);
}

template<int DIR>
__global__ __launch_bounds__(256) void kt_lr(
    const float* __restrict__ tef,
    const float* __restrict__ W, const float* __restrict__ bias,
    const int* __restrict__ t_src, const int* __restrict__ t_dst, int relu_res)
{
    const float* xin  = DIR ? g_tx1 : g_tx0;
    float*       xout = DIR ? g_tx0 : g_tx1;
    __shared__ float h[NHH+TEE];
    __shared__ int ssrc[ETT], sdst[ETT], sdeg[2*NTT];
    __shared__ float onrm[NTT], inrm[NTT];
    const int d = blockIdx.x, t = threadIdx.x;
    topo_edges_norms(t_src, t_dst, ssrc, sdst, sdeg, onrm, inrm, t);
    {
        float a0=0.f, a1=0.f;
        for (int e=0;e<ETT;e++){
            if (sdst[e]==d){
                a0 += xin[ssrc[e]*NHH+t]*onrm[ssrc[e]];
                if (t<TEE) a1 += tef[e*TEE+t];
            }
        }
        h[t]=a0;
        if (t<TEE) h[NHH+t]=a1;
    }
    __syncthreads();
    float acc=0.f;
    for (int k=0;k<NHH+TEE;k++) acc += h[k]*W[(size_t)k*NHH+t];
    float val = acc*inrm[d] + bias[t];
    xout[d*NHH+t] = relu_res ? (xin[d*NHH+t]*onrm[d] + fmaxf(val,0.f)) : val;
}

__global__ __launch_bounds__(256) void k_v0(const float* __restrict__ cW0, const int* __restrict__ tgroups){
    __shared__ float srt[NHH];
    int b=blockIdx.x, c=threadIdx.x;
    int i0=clampi(tgroups[b*2+0],0,NTT-1), i1=clampi(tgroups[b*2+1],0,NTT-1);
    srt[c]=fmaxf(g_tx1[i0*NHH+c]+g_tx1[i1*NHH+c],0.f);
    __syncthreads();
    const float* Wm = cW0 + (size_t)(CFF+OPEE + b*NHH)*NHH;
    float acc=0.f;
    for (int j=0;j<NHH;j++) acc += srt[j]*Wm[(size_t)j*NHH+c];
    g_v0p[b*NHH+c]=acc;
}

// ---------------- layer-0 gather: one wave per node, shfl-resident edge scalars ----------------
__global__ __launch_bounds__(256) void k_gather0(
    const int* __restrict__ ctypes,
    const float* __restrict__ cfeats, const float* __restrict__ opemb)
{
    const int wv = threadIdx.x >> 6, lane = threadIdx.x & 63;
    const int d = blockIdx.x*4 + wv;
    int b = g_off[d], e = g_off[d+1];
    int deg = e - b;
    int sv = 0; float onv = 0.f; int ctv = 0;
    if (lane < deg){
        int s = g_srcarr[b+lane];
        sv = s; onv = g_onorm[s]; ctv = clampi(ctypes[s],0,255);
    }
    float a_cf=0.f, a_op=0.f, aon=0.f;
    for (int i=0;i<deg;i++){
        int s; float on; int ct;
        if (i < 64){ s = __shfl(sv,i&63); on = __shfl(onv,i&63); ct = __shfl(ctv,i&63); }
        else { s = g_srcarr[b+i]; on = g_onorm[s]; ct = clampi(ctypes[s],0,255); }
        a_cf += fmaxf(cfeats[(size_t)s*CFF+lane],0.f)*on;
        if (lane < OPEE) a_op += fmaxf(opemb[ct*OPEE+lane],0.f)*on;
        aon += on;
    }
    ushort* row = g_hf0 + (size_t)d*HFB0;
    row[lane] = f2bu(a_cf);
    if (lane < OPEE)  row[CFF+lane] = f2bu(a_op);
    if (lane == 4)    g_son[d] = aon;
}

// ---------------- layer-0 MFMA GEMM: writes f32 xn0 + bf16 mirror (v0p summed inline) ----------------
__global__ __launch_bounds__(256) void k_gemm0(const float* __restrict__ cb0){
    const int d0 = blockIdx.x*16;
    const int w = threadIdx.x>>6, l = threadIdx.x&63;
    const ushort* arow = g_hf0 + (size_t)(d0 + (l&15))*HFB0 + 8*(l>>4);
    f32x4 acc0={0,0,0,0}, acc1={0,0,0,0}, acc2={0,0,0,0}, acc3={0,0,0,0};
    for (int kt=0; kt<3; kt++){
        bf16x8 a = *(const bf16x8*)(arow + kt*32);
        const ushort* bp = g_wpk0 + ((size_t)((kt*16 + w*4)*64 + l))*8;
        bf16x8 b0 = *(const bf16x8*)(bp);
        bf16x8 b1 = *(const bf16x8*)(bp + 64*8);
        bf16x8 b2 = *(const bf16x8*)(bp + 2*64*8);
        bf16x8 b3 = *(const bf16x8*)(bp + 3*64*8);
        acc0 = __builtin_amdgcn_mfma_f32_16x16x32_bf16(a, b0, acc0, 0,0,0);
        acc1 = __builtin_amdgcn_mfma_f32_16x16x32_bf16(a, b1, acc1, 0,0,0);
        acc2 = __builtin_amdgcn_mfma_f32_16x16x32_bf16(a, b2, acc2, 0,0,0);
        acc3 = __builtin_amdgcn_mfma_f32_16x16x32_bf16(a, b3, acc3, 0,0,0);
    }
    const int rb = (l>>4)*4, cb = w*64 + (l&15);
    #define EPI0(ACC, NT) { \
        int col = cb + (NT)*16; float bb = cb0[col]; \
        float v0c = 0.f; \
        _Pragma("unroll") for (int b8=0;b8<TGG;b8++) v0c += g_v0p[b8*NHH+col]; \
        _Pragma("unroll") for (int r=0;r<4;r++){ \
            int d = d0 + rb + r; \
            float val = (ACC[r] + g_son[d]*v0c)*g_inorm[d] + bb; \
            float xn = fmaxf(val,0.f)*g_onorm[d]; \
            g_x0 [(size_t)d*NHH+col] = xn; \
            g_xb0[(size_t)d*NHH+col] = f2bu(xn); } }
    EPI0(acc0,0) EPI0(acc1,1) EPI0(acc2,2) EPI0(acc3,3)
    #undef EPI0
}

// ---------------- recurrent gather: one wave per node, shfl-resident sources ----------------
template<int DIR>   // DIR=0: read g_xb0, DIR=1: read g_xb1
__global__ __launch_bounds__(256) void k_gather(){
    const ushort* xb = DIR ? g_xb1 : g_xb0;
    const int wv = threadIdx.x >> 6, lane = threadIdx.x & 63;
    const int d = blockIdx.x*4 + wv;
    int b = g_off[d], e = g_off[d+1];
    int deg = e - b;
    int sv = (lane < deg) ? g_srcarr[b+lane] : 0;
    float a0=0.f,a1=0.f,a2=0.f,a3=0.f;
    for (int i=0;i<deg;i++){
        int s = (i < 64) ? __shfl(sv,i&63) : g_srcarr[b+i];
        ushort4 v = *(const ushort4*)(xb + (size_t)s*NHH + 4*lane);
        a0 += bu2f(v.x); a1 += bu2f(v.y); a2 += bu2f(v.z); a3 += bu2f(v.w);
    }
    ushort4 o;
    o.x=f2bu(a0); o.y=f2bu(a1); o.z=f2bu(a2); o.w=f2bu(a3);
    *(ushort4*)(g_hf + (size_t)d*HFB + 4*lane) = o;   // [256:288] tail pre-baked by k_sortfill
}

// ---------------- recurrent MFMA GEMM ----------------
template<int DIR>   // DIR=0: residual/in g_x0 -> out g_x1(+xb1); DIR=1: reverse
__global__ __launch_bounds__(256) void k_gemmr(
    int loff, const float* __restrict__ bias, int relu_res)
{
    const float* xnin = DIR ? g_x1 : g_x0;
    float*       xout = DIR ? g_x0 : g_x1;
    ushort*      xbout= DIR ? g_xb0 : g_xb1;
    const int d0 = blockIdx.x*16;
    const int w = threadIdx.x>>6, l = threadIdx.x&63;
    const ushort* arow = g_hf + (size_t)(d0 + (l&15))*HFB + 8*(l>>4);
    f32x4 acc0={0,0,0,0}, acc1={0,0,0,0}, acc2={0,0,0,0}, acc3={0,0,0,0};
    for (int kt=0; kt<9; kt++){
        bf16x8 a = *(const bf16x8*)(arow + kt*32);
        const ushort* bp = g_wpk + ((size_t)(((loff+kt)*16 + w*4)*64 + l))*8;
        bf16x8 b0 = *(const bf16x8*)(bp);
        bf16x8 b1 = *(const bf16x8*)(bp + 64*8);
        bf16x8 b2 = *(const bf16x8*)(bp + 2*64*8);
        bf16x8 b3 = *(const bf16x8*)(bp + 3*64*8);
        acc0 = __builtin_amdgcn_mfma_f32_16x16x32_bf16(a, b0, acc0, 0,0,0);
        acc1 = __builtin_amdgcn_mfma_f32_16x16x32_bf16(a, b1, acc1, 0,0,0);
        acc2 = __builtin_amdgcn_mfma_f32_16x16x32_bf16(a, b2, acc2, 0,0,0);
        acc3 = __builtin_amdgcn_mfma_f32_16x16x32_bf16(a, b3, acc3, 0,0,0);
    }
    const int rb = (l>>4)*4, cb = w*64 + (l&15);
    #define EPIR(ACC, NT) { \
        int col = cb + (NT)*16; float bb = bias[col]; \
        _Pragma("unroll") for (int r=0;r<4;r++){ \
            int d = d0 + rb + r; \
            float val = ACC[r]*g_inorm[d] + bb; \
            if (relu_res){ \
                float y = xnin[(size_t)d*NHH+col] + fmaxf(val,0.f); \
                float yn = y*g_onorm[d]; \
                xout [(size_t)d*NHH+col] = yn; \
                xbout[(size_t)d*NHH+col] = f2bu(yn); \
            } else { \
                xout[(size_t)d*NHH+col] = val; \
            } } }
    EPIR(acc0,0) EPIR(acc1,1) EPIR(acc2,2) EPIR(acc3,3)
    #undef EPIR
}

// ---------------- fused pooling + heads (block g pools its own group, 4x25 partial order) ----------------
__global__ __launch_bounds__(256) void k_heads(
    const int* __restrict__ cgroups,
    const float* __restrict__ sW, const float* __restrict__ sb,
    const float* __restrict__ nW, const float* __restrict__ nb, float* __restrict__ out)
{
    __shared__ float red[256];
    __shared__ float z[9];
    int g=blockIdx.x, t=threadIdx.x;
    float sp[4];
    #pragma unroll
    for (int p=0;p<4;p++){
        float s=0.f;
        for (int i=p*25;i<p*25+25;i++){
            int idx=clampi(cgroups[g*GSZ+i],0,NCN-1);
            s += g_x1[(size_t)idx*NHH+t];
        }
        sp[p]=s;
    }
    float e = ((sp[0]+sp[1])+sp[2])+sp[3];
    for (int j=0;j<9;j++){
        float w = (j==0) ? nW[t] : sW[t*TGG+(j-1)];
        red[t]=e*w; __syncthreads();
        for (int s=128;s>0;s>>=1){ if (t<s) red[t]+=red[t+s]; __syncthreads(); }
        if (t==0) z[j]=red[0];
        __syncthreads();
    }
    if (t==0){
        float z0 = z[0] + nb[0];
        float lsig = fminf(z0,0.f) - log1pf(expf(-fabsf(z0)));
        out[g*9+0]=lsig;
        float zz[8]; float m=-1e30f;
        for (int j=0;j<8;j++){ zz[j]=z[j+1]+sb[j]; m=fmaxf(m,zz[j]); }
        float s=0.f;
        for (int j=0;j<8;j++) s+=expf(zz[j]-m);
        float lse=m+logf(s);
        for (int j=0;j<8;j++) out[g*9+1+j]=zz[j]-lse;
    }
}

extern "C" void kernel_launch(void* const* d_in, const int* in_sizes, int n_in,
                              void* d_out, int out_size, void* d_ws, size_t ws_size,
                              hipStream_t stream) {
    const int expect[24] = {
        NCN*CFF, ECN*CEE, NTT*TFF, ETT*TEE, 256*OPEE,
        (TFF+TEE)*NHH, NHH, 3*(NHH+TEE)*NHH, 3*NHH,
        (CFF+OPEE+TGG*NHH+CEE)*NHH, NHH, 5*(NHH+CEE)*NHH, 5*NHH,
        NHH*TGG, TGG, NHH, 1,
        NCN, ECN, ECN, ETT, ETT, GCN*GSZ, TGG*2
    };
    if (n_in < 24){
        k_badsize<<<(out_size+255)/256,256,0,stream>>>((float*)d_out, out_size, 2.0e6f);
        return;
    }
    for (int i=0;i<24;i++){
        if (in_sizes[i] != expect[i]){
            k_badsize<<<(out_size+255)/256,256,0,stream>>>((float*)d_out, out_size, 1.0e6f+(float)i);
            return;
        }
    }

    const float* cfeats = (const float*)d_in[0];
    const float* cef    = (const float*)d_in[1];
    const float* tfeats = (const float*)d_in[2];
    const float* tef    = (const float*)d_in[3];
    const float* opemb  = (const float*)d_in[4];
    const float* tW0    = (const float*)d_in[5];
    const float* tb0    = (const float*)d_in[6];
    const float* tWr    = (const float*)d_in[7];
    const float* tbr    = (const float*)d_in[8];
    const float* cW0    = (const float*)d_in[9];
    const float* cb0    = (const float*)d_in[10];
    const float* cWr    = (const float*)d_in[11];
    const float* cbr    = (const float*)d_in[12];
    const float* sW     = (const float*)d_in[13];
    const float* sb     = (const float*)d_in[14];
    const float* nW     = (const float*)d_in[15];
    const float* nb     = (const float*)d_in[16];
    const int* ctypes   = (const int*)d_in[17];
    const int* c_src    = (const int*)d_in[18];
    const int* c_dst    = (const int*)d_in[19];
    const int* t_src    = (const int*)d_in[20];
    const int* t_dst    = (const int*)d_in[21];
    const int* cgroups  = (const int*)d_in[22];
    const int* tgroups  = (const int*)d_in[23];

    const int EB = (ECN+255)/256;

    k_prep0   <<<232, 256, 0, stream>>>(cWr, cW0);
    k_degrees <<<EB, 256, 0, stream>>>(c_src, c_dst);
    k_scan    <<<1, 1024, 0, stream>>>();
    k_scatter <<<EB, 256, 0, stream>>>(c_dst);
    k_sortfill<<<NCN/4, 256, 0, stream>>>(c_src, cef);

    // topo GNN (f32)
    kt_l0    <<<NTT, 256, 0, stream>>>(tfeats, tef, tW0, tb0, t_src, t_dst);
    kt_lr<0> <<<NTT, 256, 0, stream>>>(tef, tWr + (size_t)0*(NHH+TEE)*NHH, tbr + 0*NHH, t_src, t_dst, 1);
    kt_lr<1> <<<NTT, 256, 0, stream>>>(tef, tWr + (size_t)1*(NHH+TEE)*NHH, tbr + 1*NHH, t_src, t_dst, 1);
    kt_lr<0> <<<NTT, 256, 0, stream>>>(tef, tWr + (size_t)2*(NHH+TEE)*NHH, tbr + 2*NHH, t_src, t_dst, 0);
    k_v0     <<<TGG, 256, 0, stream>>>(cW0, tgroups);

    // cGNN layer 0
    k_gather0<<<NCN/4, 256, 0, stream>>>(ctypes, cfeats, opemb);
    k_gemm0  <<<NCN/16, 256, 0, stream>>>(cb0);

    // 5 recurrent layers: x0 -> x1 -> x0 -> x1 -> x0 -> x1 (final raw f32 in g_x1)
    k_gather<0><<<NCN/4, 256, 0, stream>>>();
    k_gemmr <0><<<NCN/16, 256, 0, stream>>>(0*9, cbr + 0*NHH, 1);
    k_gather<1><<<NCN/4, 256, 0, stream>>>();
    k_gemmr <1><<<NCN/16, 256, 0, stream>>>(1*9, cbr + 1*NHH, 1);
    k_gather<0><<<NCN/4, 256, 0, stream>>>();
    k_gemmr <0><<<NCN/16, 256, 0, stream>>>(2*9, cbr + 2*NHH, 1);
    k_gather<1><<<NCN/4, 256, 0, stream>>>();
    k_gemmr <1><<<NCN/16, 256, 0, stream>>>(3*9, cbr + 3*NHH, 1);
    k_gather<0><<<NCN/4, 256, 0, stream>>>();
    k_gemmr <0><<<NCN/16, 256, 0, stream>>>(4*9, cbr + 4*NHH, 0);

    k_heads<<<GCN, 256, 0, stream>>>(cgroups, sW, sb, nW, nb, (float*)d_out);
}

// Round 17
// 269.132 us; speedup vs baseline: 1.2770x; 1.1583x over previous
//
#include <hip/hip_runtime.h>
#include <hip/hip_bf16.h>

#define NCN 10000   // computation nodes
#define ECN 120000  // computation edges
#define NHH 256     // hidden
#define CEE 16      // cedge feat dim
#define GCN 100     // cgroups
#define GSZ 100     // nodes per cgroup
#define NTT 16      // topo nodes
#define ETT 64      // topo edges
#define TGG 8       // tgroups
#define OPEE 4
#define CFF 64
#define TFF 32
#define TEE 16
#define HFW 272     // true K (256 + 16 eagg)
#define HFB 288     // padded K for MFMA (9*32)
#define HFB0 96     // layer-0 padded K (3*32)
#define NPACKR (5*9*16*64)   // 46080 packwr items -> 180 blocks
#define NPACK0 (3*16*64)     // 3072 packw0 items  -> 12 blocks
#define EBLK ((ECN+255)/256) // 469
#define TSPAN ((NHH+TEE)*NHH)

typedef __attribute__((ext_vector_type(8))) short bf16x8;
typedef __attribute__((ext_vector_type(4))) float f32x4;

// ---------- static device scratch (no d_ws dependency) ----------
__device__ int    g_indeg[NCN];
__device__ int    g_outdeg[NCN];
__device__ int    g_cursor[NCN];
__device__ int    g_off[NCN+1];
__device__ int    g_eid[ECN];
__device__ int    g_srcarr[ECN];
__device__ float  g_onorm[NCN];
__device__ float  g_inorm[NCN];
__device__ float  g_son[NCN];
__device__ float  g_tx0[NTT*NHH];
__device__ float  g_tx1[NTT*NHH];
__device__ float  g_v0p[TGG*NHH];
__device__ float  g_x0[(size_t)NCN*NHH];     // f32 xn state (normalized) / final raw
__device__ float  g_x1[(size_t)NCN*NHH];
__device__ ushort g_xb0[(size_t)NCN*NHH];    // bf16 mirror of xn (gather input)
__device__ ushort g_xb1[(size_t)NCN*NHH];
__device__ ushort g_hf [(size_t)NCN*HFB];    // bf16 gathered rows; [256:272]=eagg, [272:288]=0
__device__ ushort g_hf0[(size_t)NCN*HFB0];   // bf16 layer-0 rows
__device__ ushort g_wpk [NPACKR*8];          // cWr packed into B-fragment order
__device__ ushort g_wpk0[NPACK0*8];          // cW0 packed (k=68..71 zeroed; v0 term in f32 epilogue)

__device__ __forceinline__ int clampi(int v,int lo,int hi){ return v<lo?lo:(v>hi?hi:v); }
__device__ __forceinline__ ushort f2bu(float f){ __hip_bfloat16 h=__float2bfloat16(f); return *reinterpret_cast<ushort*>(&h); }
__device__ __forceinline__ float  bu2f(ushort u){ return __uint_as_float(((unsigned)u)<<16); }

__global__ __launch_bounds__(256) void k_badsize(float* out, int n, float code){
    int i = blockIdx.x*256 + threadIdx.x;
    if (i < n) out[i] = code;
}

// ---------------- topo GNN device bodies (16 blocks each, guarded for >=256-thread blocks) ----------------
__device__ __forceinline__ void topo_edges_norms(
    const int* __restrict__ t_src, const int* __restrict__ t_dst,
    int* ssrc, int* sdst, int* sdeg, float* onrm, float* inrm, int t)
{
    if (t < 2*NTT) sdeg[t]=0;
    __syncthreads();
    if (t < ETT){
        int s=clampi(t_src[t],0,NTT-1), d=clampi(t_dst[t],0,NTT-1);
        ssrc[t]=s; sdst[t]=d;
        atomicAdd(&sdeg[s],1); atomicAdd(&sdeg[NTT+d],1);
    }
    __syncthreads();
    if (t < NTT){
        onrm[t]=rsqrtf((float)max(sdeg[t],1));
        inrm[t]=rsqrtf((float)max(sdeg[NTT+t],1));
    }
    __syncthreads();
}

__device__ __forceinline__ void topo_l0_body(
    const float* __restrict__ tfeats, const float* __restrict__ tef,
    const float* __restrict__ tW0, const float* __restrict__ tb0,
    const int* __restrict__ t_src, const int* __restrict__ t_dst, int d, int t)
{
    __shared__ float h0[48];
    __shared__ int ssrc[ETT], sdst[ETT], sdeg[2*NTT];
    __shared__ float onrm[NTT], inrm[NTT];
    topo_edges_norms(t_src, t_dst, ssrc, sdst, sdeg, onrm, inrm, t);
    if (t < 48){
        float acc=0.f;
        for (int e=0;e<ETT;e++){
            if (sdst[e]==d){
                int s=ssrc[e];
                float v = (t<TFF) ? tfeats[s*TFF+t]*onrm[s] : tef[e*TEE+(t-TFF)];
                acc += fmaxf(v,0.f);
            }
        }
        h0[t]=acc;
    }
    __syncthreads();
    if (t < NHH){
        float acc=0.f;
        for (int k=0;k<48;k++) acc += h0[k]*tW0[k*NHH+t];
        g_tx0[d*NHH+t] = fmaxf(acc*inrm[d]+tb0[t], 0.f);
    }
}

__device__ __forceinline__ void topo_lr_body(
    const float* __restrict__ tef,
    const float* __restrict__ W, const float* __restrict__ bias,
    const int* __restrict__ t_src, const int* __restrict__ t_dst,
    const float* __restrict__ xin, float* __restrict__ xout,
    int relu_res, int d, int t)
{
    __shared__ float h[NHH+TEE];
    __shared__ int ssrc[ETT], sdst[ETT], sdeg[2*NTT];
    __shared__ float onrm[NTT], inrm[NTT];
    topo_edges_norms(t_src, t_dst, ssrc, sdst, sdeg, onrm, inrm, t);
    if (t < NHH){
        float a0=0.f, a1=0.f;
        for (int e=0;e<ETT;e++){
            if (sdst[e]==d){
                a0 += xin[ssrc[e]*NHH+t]*onrm[ssrc[e]];
                if (t<TEE) a1 += tef[e*TEE+t];
            }
        }
        h[t]=a0;
        if (t<TEE) h[NHH+t]=a1;
    }
    __syncthreads();
    if (t < NHH){
        float acc=0.f;
        for (int k=0;k<NHH+TEE;k++) acc += h[k]*W[(size_t)k*NHH+t];
        float val = acc*inrm[d] + bias[t];
        xout[d*NHH+t] = relu_res ? (xin[d*NHH+t]*onrm[d] + fmaxf(val,0.f)) : val;
    }
}

// -------- prep0: packwr (0..179) | packw0 (180..191) | zero (192..231) | topo-l0 (232..247) --------
__global__ __launch_bounds__(256) void k_prep0(
    const float* __restrict__ cWr, const float* __restrict__ cW0,
    const float* __restrict__ tfeats, const float* __restrict__ tef,
    const float* __restrict__ tW0, const float* __restrict__ tb0,
    const int* __restrict__ t_src, const int* __restrict__ t_dst)
{
    int bid = blockIdx.x, t = threadIdx.x;
    if (bid < 180){
        int i = bid*256 + t;
        if (i >= NPACKR) return;
        int lane = i&63, u = i>>6;
        int ntg = u&15; u >>= 4;
        int kt = u%9, l = u/9;
        int col = ntg*16 + (lane&15);
        int kb = kt*32 + 8*(lane>>4);
        #pragma unroll
        for (int j=0;j<8;j++){
            int k = kb + j;
            float v = (k < HFW) ? cWr[(size_t)l*HFW*NHH + (size_t)k*NHH + col] : 0.f;
            g_wpk[(size_t)i*8 + j] = f2bu(v);
        }
    } else if (bid < 192){
        int i = (bid-180)*256 + t;
        if (i >= NPACK0) return;
        int lane = i&63, u = i>>6;
        int ntg = u&15, kt = u>>4;
        int col = ntg*16 + (lane&15);
        int kb = kt*32 + 8*(lane>>4);
        #pragma unroll
        for (int j=0;j<8;j++){
            int k = kb + j;
            float v = 0.f;
            if (k < CFF+OPEE)            v = cW0[(size_t)k*NHH+col];
            else if (k >= 72 && k < 88)  v = cW0[(size_t)(CFF+OPEE+TGG*NHH + (k-72))*NHH + col];
            g_wpk0[(size_t)i*8 + j] = f2bu(v);
        }
    } else if (bid < 232){
        int i = (bid-192)*256 + t;
        if (i < NCN){ g_indeg[i]=0; g_outdeg[i]=0; g_cursor[i]=0; }
    } else {
        topo_l0_body(tfeats, tef, tW0, tb0, t_src, t_dst, bid-232, t);
    }
}

// -------- degrees (0..EBLK-1) | topo-lr0 (EBLK..EBLK+15) --------
__global__ __launch_bounds__(256) void k_degrees(
    const int* __restrict__ src, const int* __restrict__ dst,
    const float* __restrict__ tef, const float* __restrict__ tWr, const float* __restrict__ tbr,
    const int* __restrict__ t_src, const int* __restrict__ t_dst)
{
    int bid = blockIdx.x;
    if (bid < EBLK){
        int e = bid*256 + threadIdx.x;
        if (e < ECN){
            atomicAdd(&g_outdeg[clampi(src[e],0,NCN-1)],1);
            atomicAdd(&g_indeg [clampi(dst[e],0,NCN-1)],1);
        }
    } else {
        topo_lr_body(tef, tWr, tbr, t_src, t_dst, g_tx0, g_tx1, 1, bid-EBLK, threadIdx.x);
    }
}

// -------- scan+norms (block 0) | topo-lr1 (blocks 1..16) --------
__global__ __launch_bounds__(1024) void k_scan(
    const float* __restrict__ tef, const float* __restrict__ tWr, const float* __restrict__ tbr,
    const int* __restrict__ t_src, const int* __restrict__ t_dst)
{
    if (blockIdx.x == 0){
        __shared__ int cs[1024];
        const int CH = (NCN + 1023)/1024;
        int t = threadIdx.x;
        int base = t*CH;
        for (int j=0;j<CH;j++){
            int idx = base+j;
            if (idx < NCN){
                g_onorm[idx] = rsqrtf((float)max(g_outdeg[idx],1));
                g_inorm[idx] = rsqrtf((float)max(g_indeg[idx],1));
            }
        }
        int s = 0;
        for (int j=0;j<CH;j++){ int idx=base+j; if (idx<NCN) s += g_indeg[idx]; }
        cs[t] = s; __syncthreads();
        for (int ofs=1; ofs<1024; ofs<<=1){
            int v = (t>=ofs) ? cs[t-ofs] : 0;
            __syncthreads();
            cs[t] += v;
            __syncthreads();
        }
        int run = (t==0) ? 0 : cs[t-1];
        for (int j=0;j<CH;j++){
            int idx = base+j;
            if (idx <= NCN) g_off[idx] = run;
            if (idx < NCN) run += g_indeg[idx];
        }
    } else {
        topo_lr_body(tef, tWr + (size_t)1*TSPAN, tbr + NHH, t_src, t_dst,
                     g_tx1, g_tx0, 1, blockIdx.x-1, threadIdx.x);
    }
}

// -------- scatter (0..EBLK-1) | topo-lr2 final (EBLK..EBLK+15) --------
__global__ __launch_bounds__(256) void k_scatter(
    const int* __restrict__ dst,
    const float* __restrict__ tef, const float* __restrict__ tWr, const float* __restrict__ tbr,
    const int* __restrict__ t_src, const int* __restrict__ t_dst)
{
    int bid = blockIdx.x;
    if (bid < EBLK){
        int e = bid*256 + threadIdx.x;
        if (e < ECN){
            int d = clampi(dst[e],0,NCN-1);
            int pos = g_off[d] + atomicAdd(&g_cursor[d],1);
            g_eid[clampi(pos,0,ECN-1)] = e;
        }
    } else {
        topo_lr_body(tef, tWr + (size_t)2*TSPAN, tbr + 2*NHH, t_src, t_dst,
                     g_tx0, g_tx1, 0, bid-EBLK, threadIdx.x);
    }
}

// -------- fused sortfill + eagg + gather0 (0..2499) | v0 partials (2500..2507) --------
__global__ __launch_bounds__(256) void k_sfg0(
    const int* __restrict__ c_src, const float* __restrict__ ef,
    const int* __restrict__ ctypes, const float* __restrict__ cfeats,
    const float* __restrict__ opemb,
    const float* __restrict__ cW0, const int* __restrict__ tgroups)
{
    int bid = blockIdx.x;
    if (bid >= 2500){
        __shared__ float srt[NHH];
        int b = bid-2500, c = threadIdx.x;
        int i0=clampi(tgroups[b*2+0],0,NTT-1), i1=clampi(tgroups[b*2+1],0,NTT-1);
        srt[c]=fmaxf(g_tx1[i0*NHH+c]+g_tx1[i1*NHH+c],0.f);
        __syncthreads();
        const float* Wm = cW0 + (size_t)(CFF+OPEE + b*NHH)*NHH;
        float acc=0.f;
        for (int j=0;j<NHH;j++) acc += srt[j]*Wm[(size_t)j*NHH+c];
        g_v0p[b*NHH+c]=acc;
        return;
    }
    const int wv = threadIdx.x >> 6, lane = threadIdx.x & 63;
    const int d = bid*4 + wv;
    int b = clampi(g_off[d],0,ECN), e = clampi(g_off[d+1],b,ECN);
    int deg = e - b;
    if (deg <= 64){
        int v = (lane < deg) ? g_eid[b+lane] : 0x7fffffff;
        #pragma unroll
        for (int k=2;k<=64;k<<=1){
            #pragma unroll
            for (int j=k>>1;j>0;j>>=1){
                int p = __shfl_xor(v, j, 64);
                bool takeMin = ((lane & j)==0) == ((lane & k)==0);
                v = takeMin ? min(v,p) : max(v,p);
            }
        }
        int s = 0; float onv = 0.f; int ctv = 0;
        if (lane < deg){
            g_eid[b+lane] = v;
            s = clampi(c_src[clampi(v,0,ECN-1)],0,NCN-1);
            g_srcarr[b+lane] = s;
            onv = g_onorm[s]; ctv = clampi(ctypes[s],0,255);
        }
        // eagg (same order as before)
        float se=0.f, ser=0.f;
        for (int i=0;i<deg;i++){
            int ei = __shfl(v, i&63);
            if (lane < CEE){
                float val = ef[(size_t)clampi(ei,0,ECN-1)*CEE + lane];
                se += val; ser += fmaxf(val,0.f);
            }
        }
        if (lane < CEE){
            g_hf[(size_t)d*HFB + NHH + lane]      = f2bu(se);
            g_hf[(size_t)d*HFB + NHH + 16 + lane] = 0;
        }
        // gather0 continues in-wave with register-resident sources (identical order)
        float a_cf=0.f, a_op=0.f, aon=0.f;
        for (int i=0;i<deg;i++){
            int si = __shfl(s,i&63); float on = __shfl(onv,i&63); int ct = __shfl(ctv,i&63);
            a_cf += fmaxf(cfeats[(size_t)si*CFF+lane],0.f)*on;
            if (lane < OPEE) a_op += fmaxf(opemb[ct*OPEE+lane],0.f)*on;
            aon += on;
        }
        ushort* row = g_hf0 + (size_t)d*HFB0;
        row[lane] = f2bu(a_cf);
        if (lane < OPEE)         row[CFF+lane] = f2bu(a_op);
        if (lane >= 4 && lane<8) row[64+lane] = 0;      // cols 68..71
        if (lane < CEE)          row[72+lane] = f2bu(ser);
        if (lane >= 8 && lane<16)row[80+lane] = 0;      // cols 88..95
        if (lane == 16)          g_son[d] = aon;
    } else if (lane == 0){
        for (int i=b+1;i<e;i++){
            int key = g_eid[i]; int j = i-1;
            while (j>=b && g_eid[j]>key){ g_eid[j+1]=g_eid[j]; j--; }
            g_eid[j+1] = key;
        }
        for (int i=b;i<e;i++) g_srcarr[i] = clampi(c_src[clampi(g_eid[i],0,ECN-1)],0,NCN-1);
        ushort* row = g_hf0 + (size_t)d*HFB0;
        for (int f=0;f<CEE;f++){
            float se=0.f, ser=0.f;
            for (int i=b;i<e;i++){
                float val = ef[(size_t)clampi(g_eid[i],0,ECN-1)*CEE + f];
                se += val; ser += fmaxf(val,0.f);
            }
            g_hf[(size_t)d*HFB + NHH + f]      = f2bu(se);
            g_hf[(size_t)d*HFB + NHH + 16 + f] = 0;
            row[72+f] = f2bu(ser);
        }
        for (int c=0;c<CFF;c++){
            float a=0.f;
            for (int i=b;i<e;i++){ int si=g_srcarr[i]; a += fmaxf(cfeats[(size_t)si*CFF+c],0.f)*g_onorm[si]; }
            row[c] = f2bu(a);
        }
        for (int c=0;c<OPEE;c++){
            float a=0.f;
            for (int i=b;i<e;i++){ int si=g_srcarr[i]; int ct=clampi(ctypes[si],0,255); a += fmaxf(opemb[ct*OPEE+c],0.f)*g_onorm[si]; }
            row[CFF+c] = f2bu(a);
        }
        float aon=0.f;
        for (int i=b;i<e;i++) aon += g_onorm[g_srcarr[i]];
        g_son[d]=aon;
        for (int c=68;c<72;c++) row[c]=0;
        for (int c=88;c<96;c++) row[c]=0;
    }
}

// ---------------- layer-0 MFMA GEMM: writes f32 xn0 + bf16 mirror (v0p summed inline) ----------------
__global__ __launch_bounds__(256) void k_gemm0(const float* __restrict__ cb0){
    const int d0 = blockIdx.x*16;
    const int w = threadIdx.x>>6, l = threadIdx.x&63;
    const ushort* arow = g_hf0 + (size_t)(d0 + (l&15))*HFB0 + 8*(l>>4);
    f32x4 acc0={0,0,0,0}, acc1={0,0,0,0}, acc2={0,0,0,0}, acc3={0,0,0,0};
    for (int kt=0; kt<3; kt++){
        bf16x8 a = *(const bf16x8*)(arow + kt*32);
        const ushort* bp = g_wpk0 + ((size_t)((kt*16 + w*4)*64 + l))*8;
        bf16x8 b0 = *(const bf16x8*)(bp);
        bf16x8 b1 = *(const bf16x8*)(bp + 64*8);
        bf16x8 b2 = *(const bf16x8*)(bp + 2*64*8);
        bf16x8 b3 = *(const bf16x8*)(bp + 3*64*8);
        acc0 = __builtin_amdgcn_mfma_f32_16x16x32_bf16(a, b0, acc0, 0,0,0);
        acc1 = __builtin_amdgcn_mfma_f32_16x16x32_bf16(a, b1, acc1, 0,0,0);
        acc2 = __builtin_amdgcn_mfma_f32_16x16x32_bf16(a, b2, acc2, 0,0,0);
        acc3 = __builtin_amdgcn_mfma_f32_16x16x32_bf16(a, b3, acc3, 0,0,0);
    }
    const int rb = (l>>4)*4, cb = w*64 + (l&15);
    #define EPI0(ACC, NT) { \
        int col = cb + (NT)*16; float bb = cb0[col]; \
        float v0c = 0.f; \
        _Pragma("unroll") for (int b8=0;b8<TGG;b8++) v0c += g_v0p[b8*NHH+col]; \
        _Pragma("unroll") for (int r=0;r<4;r++){ \
            int d = d0 + rb + r; \
            float val = (ACC[r] + g_son[d]*v0c)*g_inorm[d] + bb; \
            float xn = fmaxf(val,0.f)*g_onorm[d]; \
            g_x0 [(size_t)d*NHH+col] = xn; \
            g_xb0[(size_t)d*NHH+col] = f2bu(xn); } }
    EPI0(acc0,0) EPI0(acc1,1) EPI0(acc2,2) EPI0(acc3,3)
    #undef EPI0
}

// ---------------- recurrent gather: one wave per node, shfl-resident sources ----------------
template<int DIR>   // DIR=0: read g_xb0, DIR=1: read g_xb1
__global__ __launch_bounds__(256) void k_gather(){
    const ushort* xb = DIR ? g_xb1 : g_xb0;
    const int wv = threadIdx.x >> 6, lane = threadIdx.x & 63;
    const int d = blockIdx.x*4 + wv;
    int b = g_off[d], e = g_off[d+1];
    int deg = e - b;
    int sv = (lane < deg) ? g_srcarr[b+lane] : 0;
    float a0=0.f,a1=0.f,a2=0.f,a3=0.f;
    for (int i=0;i<deg;i++){
        int s = (i < 64) ? __shfl(sv,i&63) : g_srcarr[b+i];
        ushort4 v = *(const ushort4*)(xb + (size_t)s*NHH + 4*lane);
        a0 += bu2f(v.x); a1 += bu2f(v.y); a2 += bu2f(v.z); a3 += bu2f(v.w);
    }
    ushort4 o;
    o.x=f2bu(a0); o.y=f2bu(a1); o.z=f2bu(a2); o.w=f2bu(a3);
    *(ushort4*)(g_hf + (size_t)d*HFB + 4*lane) = o;   // [256:288] tail pre-baked by k_sfg0
}

// ---------------- recurrent MFMA GEMM ----------------
template<int DIR>   // DIR=0: residual/in g_x0 -> out g_x1(+xb1); DIR=1: reverse
__global__ __launch_bounds__(256) void k_gemmr(
    int loff, const float* __restrict__ bias, int relu_res)
{
    const float* xnin = DIR ? g_x1 : g_x0;
    float*       xout = DIR ? g_x0 : g_x1;
    ushort*      xbout= DIR ? g_xb0 : g_xb1;
    const int d0 = blockIdx.x*16;
    const int w = threadIdx.x>>6, l = threadIdx.x&63;
    const ushort* arow = g_hf + (size_t)(d0 + (l&15))*HFB + 8*(l>>4);
    f32x4 acc0={0,0,0,0}, acc1={0,0,0,0}, acc2={0,0,0,0}, acc3={0,0,0,0};
    for (int kt=0; kt<9; kt++){
        bf16x8 a = *(const bf16x8*)(arow + kt*32);
        const ushort* bp = g_wpk + ((size_t)(((loff+kt)*16 + w*4)*64 + l))*8;
        bf16x8 b0 = *(const bf16x8*)(bp);
        bf16x8 b1 = *(const bf16x8*)(bp + 64*8);
        bf16x8 b2 = *(const bf16x8*)(bp + 2*64*8);
        bf16x8 b3 = *(const bf16x8*)(bp + 3*64*8);
        acc0 = __builtin_amdgcn_mfma_f32_16x16x32_bf16(a, b0, acc0, 0,0,0);
        acc1 = __builtin_amdgcn_mfma_f32_16x16x32_bf16(a, b1, acc1, 0,0,0);
        acc2 = __builtin_amdgcn_mfma_f32_16x16x32_bf16(a, b2, acc2, 0,0,0);
        acc3 = __builtin_amdgcn_mfma_f32_16x16x32_bf16(a, b3, acc3, 0,0,0);
    }
    const int rb = (l>>4)*4, cb = w*64 + (l&15);
    #define EPIR(ACC, NT) { \
        int col = cb + (NT)*16; float bb = bias[col]; \
        _Pragma("unroll") for (int r=0;r<4;r++){ \
            int d = d0 + rb + r; \
            float val = ACC[r]*g_inorm[d] + bb; \
            if (relu_res){ \
                float y = xnin[(size_t)d*NHH+col] + fmaxf(val,0.f); \
                float yn = y*g_onorm[d]; \
                xout [(size_t)d*NHH+col] = yn; \
                xbout[(size_t)d*NHH+col] = f2bu(yn); \
            } else { \
                xout[(size_t)d*NHH+col] = val; \
            } } }
    EPIR(acc0,0) EPIR(acc1,1) EPIR(acc2,2) EPIR(acc3,3)
    #undef EPIR
}

// ---------------- fused pooling + heads (block g pools its own group, 4x25 partial order) ----------------
__global__ __launch_bounds__(256) void k_heads(
    const int* __restrict__ cgroups,
    const float* __restrict__ sW, const float* __restrict__ sb,
    const float* __restrict__ nW, const float* __restrict__ nb, float* __restrict__ out)
{
    __shared__ float red[256];
    __shared__ float z[9];
    int g=blockIdx.x, t=threadIdx.x;
    float sp[4];
    #pragma unroll
    for (int p=0;p<4;p++){
        float s=0.f;
        for (int i=p*25;i<p*25+25;i++){
            int idx=clampi(cgroups[g*GSZ+i],0,NCN-1);
            s += g_x1[(size_t)idx*NHH+t];
        }
        sp[p]=s;
    }
    float e = ((sp[0]+sp[1])+sp[2])+sp[3];
    for (int j=0;j<9;j++){
        float w = (j==0) ? nW[t] : sW[t*TGG+(j-1)];
        red[t]=e*w; __syncthreads();
        for (int s=128;s>0;s>>=1){ if (t<s) red[t]+=red[t+s]; __syncthreads(); }
        if (t==0) z[j]=red[0];
        __syncthreads();
    }
    if (t==0){
        float z0 = z[0] + nb[0];
        float lsig = fminf(z0,0.f) - log1pf(expf(-fabsf(z0)));
        out[g*9+0]=lsig;
        float zz[8]; float m=-1e30f;
        for (int j=0;j<8;j++){ zz[j]=z[j+1]+sb[j]; m=fmaxf(m,zz[j]); }
        float s=0.f;
        for (int j=0;j<8;j++) s+=expf(zz[j]-m);
        float lse=m+logf(s);
        for (int j=0;j<8;j++) out[g*9+1+j]=zz[j]-lse;
    }
}

extern "C" void kernel_launch(void* const* d_in, const int* in_sizes, int n_in,
                              void* d_out, int out_size, void* d_ws, size_t ws_size,
                              hipStream_t stream) {
    const int expect[24] = {
        NCN*CFF, ECN*CEE, NTT*TFF, ETT*TEE, 256*OPEE,
        (TFF+TEE)*NHH, NHH, 3*(NHH+TEE)*NHH, 3*NHH,
        (CFF+OPEE+TGG*NHH+CEE)*NHH, NHH, 5*(NHH+CEE)*NHH, 5*NHH,
        NHH*TGG, TGG, NHH, 1,
        NCN, ECN, ECN, ETT, ETT, GCN*GSZ, TGG*2
    };
    if (n_in < 24){
        k_badsize<<<(out_size+255)/256,256,0,stream>>>((float*)d_out, out_size, 2.0e6f);
        return;
    }
    for (int i=0;i<24;i++){
        if (in_sizes[i] != expect[i]){
            k_badsize<<<(out_size+255)/256,256,0,stream>>>((float*)d_out, out_size, 1.0e6f+(float)i);
            return;
        }
    }

    const float* cfeats = (const float*)d_in[0];
    const float* cef    = (const float*)d_in[1];
    const float* tfeats = (const float*)d_in[2];
    const float* tef    = (const float*)d_in[3];
    const float* opemb  = (const float*)d_in[4];
    const float* tW0    = (const float*)d_in[5];
    const float* tb0    = (const float*)d_in[6];
    const float* tWr    = (const float*)d_in[7];
    const float* tbr    = (const float*)d_in[8];
    const float* cW0    = (const float*)d_in[9];
    const float* cb0    = (const float*)d_in[10];
    const float* cWr    = (const float*)d_in[11];
    const float* cbr    = (const float*)d_in[12];
    const float* sW     = (const float*)d_in[13];
    const float* sb     = (const float*)d_in[14];
    const float* nW     = (const float*)d_in[15];
    const float* nb     = (const float*)d_in[16];
    const int* ctypes   = (const int*)d_in[17];
    const int* c_src    = (const int*)d_in[18];
    const int* c_dst    = (const int*)d_in[19];
    const int* t_src    = (const int*)d_in[20];
    const int* t_dst    = (const int*)d_in[21];
    const int* cgroups  = (const int*)d_in[22];
    const int* tgroups  = (const int*)d_in[23];

    k_prep0  <<<248, 256, 0, stream>>>(cWr, cW0, tfeats, tef, tW0, tb0, t_src, t_dst);
    k_degrees<<<EBLK+16, 256, 0, stream>>>(c_src, c_dst, tef, tWr, tbr, t_src, t_dst);
    k_scan   <<<17, 1024, 0, stream>>>(tef, tWr, tbr, t_src, t_dst);
    k_scatter<<<EBLK+16, 256, 0, stream>>>(c_dst, tef, tWr, tbr, t_src, t_dst);
    k_sfg0   <<<2508, 256, 0, stream>>>(c_src, cef, ctypes, cfeats, opemb, cW0, tgroups);
    k_gemm0  <<<NCN/16, 256, 0, stream>>>(cb0);

    // 5 recurrent layers: x0 -> x1 -> x0 -> x1 -> x0 -> x1 (final raw f32 in g_x1)
    k_gather<0><<<NCN/4, 256, 0, stream>>>();
    k_gemmr <0><<<NCN/16, 256, 0, stream>>>(0*9, cbr + 0*NHH, 1);
    k_gather<1><<<NCN/4, 256, 0, stream>>>();
    k_gemmr <1><<<NCN/16, 256, 0, stream>>>(1*9, cbr + 1*NHH, 1);
    k_gather<0><<<NCN/4, 256, 0, stream>>>();
    k_gemmr <0><<<NCN/16, 256, 0, stream>>>(2*9, cbr + 2*NHH, 1);
    k_gather<1><<<NCN/4, 256, 0, stream>>>();
    k_gemmr <1><<<NCN/16, 256, 0, stream>>>(3*9, cbr + 3*NHH, 1);
    k_gather<0><<<NCN/4, 256, 0, stream>>>();
    k_gemmr <0><<<NCN/16, 256, 0, stream>>>(4*9, cbr + 4*NHH, 0);

    k_heads<<<GCN, 256, 0, stream>>>(cgroups, sW, sb, nW, nb, (float*)d_out);
}

// Round 18
// 249.219 us; speedup vs baseline: 1.3790x; 1.0799x over previous
//
#include <hip/hip_runtime.h>
#include <hip/hip_bf16.h>

#define NCN 10000   // computation nodes
#define ECN 120000  // computation edges
#define NHH 256     // hidden
#define CEE 16      // cedge feat dim
#define GCN 100     // cgroups
#define GSZ 100     // nodes per cgroup
#define NTT 16      // topo nodes
#define ETT 64      // topo edges
#define TGG 8       // tgroups
#define OPEE 4
#define CFF 64
#define TFF 32
#define TEE 16
#define HFW 272     // true K (256 + 16 eagg)
#define HFB 288     // padded K for MFMA (9*32)
#define HFB0 96     // layer-0 padded K (3*32)
#define NPACKR (5*9*16*64)   // 46080 packwr items -> 180 blocks
#define NPACK0 (3*16*64)     // 3072 packw0 items  -> 12 blocks
#define EBLK ((ECN+255)/256) // 469
#define TSPAN ((NHH+TEE)*NHH)

typedef __attribute__((ext_vector_type(8))) short bf16x8;
typedef __attribute__((ext_vector_type(4))) float f32x4;
typedef __attribute__((ext_vector_type(8))) ushort ushort8;

// ---------- static device scratch (no d_ws dependency) ----------
__device__ int    g_indeg[NCN];
__device__ int    g_outdeg[NCN];
__device__ int    g_cursor[NCN];
__device__ int    g_off[NCN+1];
__device__ int    g_eid[ECN];
__device__ int    g_srcarr[ECN];
__device__ float  g_onorm[NCN];
__device__ float  g_inorm[NCN];
__device__ float  g_son[NCN];
__device__ float  g_tx0[NTT*NHH];
__device__ float  g_tx1[NTT*NHH];
__device__ float  g_v0p[TGG*NHH];
__device__ float  g_x0[(size_t)NCN*NHH];     // f32 xn state (normalized) / final raw
__device__ float  g_x1[(size_t)NCN*NHH];
__device__ ushort g_xb0[(size_t)NCN*NHH];    // bf16 mirror of xn (gather input)
__device__ ushort g_xb1[(size_t)NCN*NHH];
__device__ ushort g_hf [(size_t)NCN*HFB];    // bf16 gathered rows; [256:272]=eagg, [272:288]=0
__device__ ushort g_hf0[(size_t)NCN*HFB0];   // bf16 layer-0 rows
__device__ ushort g_wpk [NPACKR*8];          // cWr packed into B-fragment order
__device__ ushort g_wpk0[NPACK0*8];          // cW0 packed (k=68..71 zeroed; v0 term in f32 epilogue)

__device__ __forceinline__ int clampi(int v,int lo,int hi){ return v<lo?lo:(v>hi?hi:v); }
__device__ __forceinline__ ushort f2bu(float f){ __hip_bfloat16 h=__float2bfloat16(f); return *reinterpret_cast<ushort*>(&h); }
__device__ __forceinline__ float  bu2f(ushort u){ return __uint_as_float(((unsigned)u)<<16); }

__global__ __launch_bounds__(256) void k_badsize(float* out, int n, float code){
    int i = blockIdx.x*256 + threadIdx.x;
    if (i < n) out[i] = code;
}

// ---------------- topo GNN device bodies (16 blocks each, guarded for >=256-thread blocks) ----------------
__device__ __forceinline__ void topo_edges_norms(
    const int* __restrict__ t_src, const int* __restrict__ t_dst,
    int* ssrc, int* sdst, int* sdeg, float* onrm, float* inrm, int t)
{
    if (t < 2*NTT) sdeg[t]=0;
    __syncthreads();
    if (t < ETT){
        int s=clampi(t_src[t],0,NTT-1), d=clampi(t_dst[t],0,NTT-1);
        ssrc[t]=s; sdst[t]=d;
        atomicAdd(&sdeg[s],1); atomicAdd(&sdeg[NTT+d],1);
    }
    __syncthreads();
    if (t < NTT){
        onrm[t]=rsqrtf((float)max(sdeg[t],1));
        inrm[t]=rsqrtf((float)max(sdeg[NTT+t],1));
    }
    __syncthreads();
}

__device__ __forceinline__ void topo_l0_body(
    const float* __restrict__ tfeats, const float* __restrict__ tef,
    const float* __restrict__ tW0, const float* __restrict__ tb0,
    const int* __restrict__ t_src, const int* __restrict__ t_dst, int d, int t)
{
    __shared__ float h0[48];
    __shared__ int ssrc[ETT], sdst[ETT], sdeg[2*NTT];
    __shared__ float onrm[NTT], inrm[NTT];
    topo_edges_norms(t_src, t_dst, ssrc, sdst, sdeg, onrm, inrm, t);
    if (t < 48){
        float acc=0.f;
        for (int e=0;e<ETT;e++){
            if (sdst[e]==d){
                int s=ssrc[e];
                float v = (t<TFF) ? tfeats[s*TFF+t]*onrm[s] : tef[e*TEE+(t-TFF)];
                acc += fmaxf(v,0.f);
            }
        }
        h0[t]=acc;
    }
    __syncthreads();
    if (t < NHH){
        float acc=0.f;
        for (int k=0;k<48;k++) acc += h0[k]*tW0[k*NHH+t];
        g_tx0[d*NHH+t] = fmaxf(acc*inrm[d]+tb0[t], 0.f);
    }
}

__device__ __forceinline__ void topo_lr_body(
    const float* __restrict__ tef,
    const float* __restrict__ W, const float* __restrict__ bias,
    const int* __restrict__ t_src, const int* __restrict__ t_dst,
    const float* __restrict__ xin, float* __restrict__ xout,
    int relu_res, int d, int t)
{
    __shared__ float h[NHH+TEE];
    __shared__ int ssrc[ETT], sdst[ETT], sdeg[2*NTT];
    __shared__ float onrm[NTT], inrm[NTT];
    topo_edges_norms(t_src, t_dst, ssrc, sdst, sdeg, onrm, inrm, t);
    if (t < NHH){
        float a0=0.f, a1=0.f;
        for (int e=0;e<ETT;e++){
            if (sdst[e]==d){
                a0 += xin[ssrc[e]*NHH+t]*onrm[ssrc[e]];
                if (t<TEE) a1 += tef[e*TEE+t];
            }
        }
        h[t]=a0;
        if (t<TEE) h[NHH+t]=a1;
    }
    __syncthreads();
    if (t < NHH){
        float acc=0.f;
        for (int k=0;k<NHH+TEE;k++) acc += h[k]*W[(size_t)k*NHH+t];
        float val = acc*inrm[d] + bias[t];
        xout[d*NHH+t] = relu_res ? (xin[d*NHH+t]*onrm[d] + fmaxf(val,0.f)) : val;
    }
}

// -------- prep0: packwr (0..179) | packw0 (180..191) | zero (192..231) | topo-l0 (232..247) --------
__global__ __launch_bounds__(256) void k_prep0(
    const float* __restrict__ cWr, const float* __restrict__ cW0,
    const float* __restrict__ tfeats, const float* __restrict__ tef,
    const float* __restrict__ tW0, const float* __restrict__ tb0,
    const int* __restrict__ t_src, const int* __restrict__ t_dst)
{
    int bid = blockIdx.x, t = threadIdx.x;
    if (bid < 180){
        int i = bid*256 + t;
        if (i >= NPACKR) return;
        int lane = i&63, u = i>>6;
        int ntg = u&15; u >>= 4;
        int kt = u%9, l = u/9;
        int col = ntg*16 + (lane&15);
        int kb = kt*32 + 8*(lane>>4);
        #pragma unroll
        for (int j=0;j<8;j++){
            int k = kb + j;
            float v = (k < HFW) ? cWr[(size_t)l*HFW*NHH + (size_t)k*NHH + col] : 0.f;
            g_wpk[(size_t)i*8 + j] = f2bu(v);
        }
    } else if (bid < 192){
        int i = (bid-180)*256 + t;
        if (i >= NPACK0) return;
        int lane = i&63, u = i>>6;
        int ntg = u&15, kt = u>>4;
        int col = ntg*16 + (lane&15);
        int kb = kt*32 + 8*(lane>>4);
        #pragma unroll
        for (int j=0;j<8;j++){
            int k = kb + j;
            float v = 0.f;
            if (k < CFF+OPEE)            v = cW0[(size_t)k*NHH+col];
            else if (k >= 72 && k < 88)  v = cW0[(size_t)(CFF+OPEE+TGG*NHH + (k-72))*NHH + col];
            g_wpk0[(size_t)i*8 + j] = f2bu(v);
        }
    } else if (bid < 232){
        int i = (bid-192)*256 + t;
        if (i < NCN){ g_indeg[i]=0; g_outdeg[i]=0; g_cursor[i]=0; }
    } else {
        topo_l0_body(tfeats, tef, tW0, tb0, t_src, t_dst, bid-232, t);
    }
}

// -------- degrees (0..EBLK-1) | topo-lr0 (EBLK..EBLK+15) --------
__global__ __launch_bounds__(256) void k_degrees(
    const int* __restrict__ src, const int* __restrict__ dst,
    const float* __restrict__ tef, const float* __restrict__ tWr, const float* __restrict__ tbr,
    const int* __restrict__ t_src, const int* __restrict__ t_dst)
{
    int bid = blockIdx.x;
    if (bid < EBLK){
        int e = bid*256 + threadIdx.x;
        if (e < ECN){
            atomicAdd(&g_outdeg[clampi(src[e],0,NCN-1)],1);
            atomicAdd(&g_indeg [clampi(dst[e],0,NCN-1)],1);
        }
    } else {
        topo_lr_body(tef, tWr, tbr, t_src, t_dst, g_tx0, g_tx1, 1, bid-EBLK, threadIdx.x);
    }
}

// -------- scan+norms (block 0) | topo-lr1 (blocks 1..16) --------
__global__ __launch_bounds__(1024) void k_scan(
    const float* __restrict__ tef, const float* __restrict__ tWr, const float* __restrict__ tbr,
    const int* __restrict__ t_src, const int* __restrict__ t_dst)
{
    if (blockIdx.x == 0){
        __shared__ int cs[1024];
        const int CH = (NCN + 1023)/1024;
        int t = threadIdx.x;
        int base = t*CH;
        for (int j=0;j<CH;j++){
            int idx = base+j;
            if (idx < NCN){
                g_onorm[idx] = rsqrtf((float)max(g_outdeg[idx],1));
                g_inorm[idx] = rsqrtf((float)max(g_indeg[idx],1));
            }
        }
        int s = 0;
        for (int j=0;j<CH;j++){ int idx=base+j; if (idx<NCN) s += g_indeg[idx]; }
        cs[t] = s; __syncthreads();
        for (int ofs=1; ofs<1024; ofs<<=1){
            int v = (t>=ofs) ? cs[t-ofs] : 0;
            __syncthreads();
            cs[t] += v;
            __syncthreads();
        }
        int run = (t==0) ? 0 : cs[t-1];
        for (int j=0;j<CH;j++){
            int idx = base+j;
            if (idx <= NCN) g_off[idx] = run;
            if (idx < NCN) run += g_indeg[idx];
        }
    } else {
        topo_lr_body(tef, tWr + (size_t)1*TSPAN, tbr + NHH, t_src, t_dst,
                     g_tx1, g_tx0, 1, blockIdx.x-1, threadIdx.x);
    }
}

// -------- scatter (0..EBLK-1) | topo-lr2 final (EBLK..EBLK+15) --------
__global__ __launch_bounds__(256) void k_scatter(
    const int* __restrict__ dst,
    const float* __restrict__ tef, const float* __restrict__ tWr, const float* __restrict__ tbr,
    const int* __restrict__ t_src, const int* __restrict__ t_dst)
{
    int bid = blockIdx.x;
    if (bid < EBLK){
        int e = bid*256 + threadIdx.x;
        if (e < ECN){
            int d = clampi(dst[e],0,NCN-1);
            int pos = g_off[d] + atomicAdd(&g_cursor[d],1);
            g_eid[clampi(pos,0,ECN-1)] = e;
        }
    } else {
        topo_lr_body(tef, tWr + (size_t)2*TSPAN, tbr + 2*NHH, t_src, t_dst,
                     g_tx0, g_tx1, 0, bid-EBLK, threadIdx.x);
    }
}

// -------- fused sortfill + eagg + gather0 (0..2499) | v0 partials (2500..2507) --------
__global__ __launch_bounds__(256) void k_sfg0(
    const int* __restrict__ c_src, const float* __restrict__ ef,
    const int* __restrict__ ctypes, const float* __restrict__ cfeats,
    const float* __restrict__ opemb,
    const float* __restrict__ cW0, const int* __restrict__ tgroups)
{
    int bid = blockIdx.x;
    if (bid >= 2500){
        __shared__ float srt[NHH];
        int b = bid-2500, c = threadIdx.x;
        int i0=clampi(tgroups[b*2+0],0,NTT-1), i1=clampi(tgroups[b*2+1],0,NTT-1);
        srt[c]=fmaxf(g_tx1[i0*NHH+c]+g_tx1[i1*NHH+c],0.f);
        __syncthreads();
        const float* Wm = cW0 + (size_t)(CFF+OPEE + b*NHH)*NHH;
        float acc=0.f;
        for (int j=0;j<NHH;j++) acc += srt[j]*Wm[(size_t)j*NHH+c];
        g_v0p[b*NHH+c]=acc;
        return;
    }
    const int wv = threadIdx.x >> 6, lane = threadIdx.x & 63;
    const int d = bid*4 + wv;
    int b = clampi(g_off[d],0,ECN), e = clampi(g_off[d+1],b,ECN);
    int deg = e - b;
    if (deg <= 64){
        int v = (lane < deg) ? g_eid[b+lane] : 0x7fffffff;
        #pragma unroll
        for (int k=2;k<=64;k<<=1){
            #pragma unroll
            for (int j=k>>1;j>0;j>>=1){
                int p = __shfl_xor(v, j, 64);
                bool takeMin = ((lane & j)==0) == ((lane & k)==0);
                v = takeMin ? min(v,p) : max(v,p);
            }
        }
        int s = 0; float onv = 0.f; int ctv = 0;
        if (lane < deg){
            g_eid[b+lane] = v;
            s = clampi(c_src[clampi(v,0,ECN-1)],0,NCN-1);
            g_srcarr[b+lane] = s;
            onv = g_onorm[s]; ctv = clampi(ctypes[s],0,255);
        }
        float se=0.f, ser=0.f;
        for (int i=0;i<deg;i++){
            int ei = __shfl(v, i&63);
            if (lane < CEE){
                float val = ef[(size_t)clampi(ei,0,ECN-1)*CEE + lane];
                se += val; ser += fmaxf(val,0.f);
            }
        }
        if (lane < CEE){
            g_hf[(size_t)d*HFB + NHH + lane]      = f2bu(se);
            g_hf[(size_t)d*HFB + NHH + 16 + lane] = 0;
        }
        float a_cf=0.f, a_op=0.f, aon=0.f;
        for (int i=0;i<deg;i++){
            int si = __shfl(s,i&63); float on = __shfl(onv,i&63); int ct = __shfl(ctv,i&63);
            a_cf += fmaxf(cfeats[(size_t)si*CFF+lane],0.f)*on;
            if (lane < OPEE) a_op += fmaxf(opemb[ct*OPEE+lane],0.f)*on;
            aon += on;
        }
        ushort* row = g_hf0 + (size_t)d*HFB0;
        row[lane] = f2bu(a_cf);
        if (lane < OPEE)         row[CFF+lane] = f2bu(a_op);
        if (lane >= 4 && lane<8) row[64+lane] = 0;      // cols 68..71
        if (lane < CEE)          row[72+lane] = f2bu(ser);
        if (lane >= 8 && lane<16)row[80+lane] = 0;      // cols 88..95
        if (lane == 16)          g_son[d] = aon;
    } else if (lane == 0){
        for (int i=b+1;i<e;i++){
            int key = g_eid[i]; int j = i-1;
            while (j>=b && g_eid[j]>key){ g_eid[j+1]=g_eid[j]; j--; }
            g_eid[j+1] = key;
        }
        for (int i=b;i<e;i++) g_srcarr[i] = clampi(c_src[clampi(g_eid[i],0,ECN-1)],0,NCN-1);
        ushort* row = g_hf0 + (size_t)d*HFB0;
        for (int f=0;f<CEE;f++){
            float se=0.f, ser=0.f;
            for (int i=b;i<e;i++){
                float val = ef[(size_t)clampi(g_eid[i],0,ECN-1)*CEE + f];
                se += val; ser += fmaxf(val,0.f);
            }
            g_hf[(size_t)d*HFB + NHH + f]      = f2bu(se);
            g_hf[(size_t)d*HFB + NHH + 16 + f] = 0;
            row[72+f] = f2bu(ser);
        }
        for (int c=0;c<CFF;c++){
            float a=0.f;
            for (int i=b;i<e;i++){ int si=g_srcarr[i]; a += fmaxf(cfeats[(size_t)si*CFF+c],0.f)*g_onorm[si]; }
            row[c] = f2bu(a);
        }
        for (int c=0;c<OPEE;c++){
            float a=0.f;
            for (int i=b;i<e;i++){ int si=g_srcarr[i]; int ct=clampi(ctypes[si],0,255); a += fmaxf(opemb[ct*OPEE+c],0.f)*g_onorm[si]; }
            row[CFF+c] = f2bu(a);
        }
        float aon=0.f;
        for (int i=b;i<e;i++) aon += g_onorm[g_srcarr[i]];
        g_son[d]=aon;
        for (int c=68;c<72;c++) row[c]=0;
        for (int c=88;c<96;c++) row[c]=0;
    }
}

// ---------------- layer-0 MFMA GEMM: writes f32 xn0 + bf16 mirror (v0p summed inline) ----------------
__global__ __launch_bounds__(256) void k_gemm0(const float* __restrict__ cb0){
    const int d0 = blockIdx.x*16;
    const int w = threadIdx.x>>6, l = threadIdx.x&63;
    const ushort* arow = g_hf0 + (size_t)(d0 + (l&15))*HFB0 + 8*(l>>4);
    f32x4 acc0={0,0,0,0}, acc1={0,0,0,0}, acc2={0,0,0,0}, acc3={0,0,0,0};
    for (int kt=0; kt<3; kt++){
        bf16x8 a = *(const bf16x8*)(arow + kt*32);
        const ushort* bp = g_wpk0 + ((size_t)((kt*16 + w*4)*64 + l))*8;
        bf16x8 b0 = *(const bf16x8*)(bp);
        bf16x8 b1 = *(const bf16x8*)(bp + 64*8);
        bf16x8 b2 = *(const bf16x8*)(bp + 2*64*8);
        bf16x8 b3 = *(const bf16x8*)(bp + 3*64*8);
        acc0 = __builtin_amdgcn_mfma_f32_16x16x32_bf16(a, b0, acc0, 0,0,0);
        acc1 = __builtin_amdgcn_mfma_f32_16x16x32_bf16(a, b1, acc1, 0,0,0);
        acc2 = __builtin_amdgcn_mfma_f32_16x16x32_bf16(a, b2, acc2, 0,0,0);
        acc3 = __builtin_amdgcn_mfma_f32_16x16x32_bf16(a, b3, acc3, 0,0,0);
    }
    const int rb = (l>>4)*4, cb = w*64 + (l&15);
    #define EPI0(ACC, NT) { \
        int col = cb + (NT)*16; float bb = cb0[col]; \
        float v0c = 0.f; \
        _Pragma("unroll") for (int b8=0;b8<TGG;b8++) v0c += g_v0p[b8*NHH+col]; \
        _Pragma("unroll") for (int r=0;r<4;r++){ \
            int d = d0 + rb + r; \
            float val = (ACC[r] + g_son[d]*v0c)*g_inorm[d] + bb; \
            float xn = fmaxf(val,0.f)*g_onorm[d]; \
            g_x0 [(size_t)d*NHH+col] = xn; \
            g_xb0[(size_t)d*NHH+col] = f2bu(xn); } }
    EPI0(acc0,0) EPI0(acc1,1) EPI0(acc2,2) EPI0(acc3,3)
    #undef EPI0
}

// ------- recurrent gather: wave per node, 2 edges/iter via 16B loads, shfl-xor combine -------
template<int DIR>   // DIR=0: read g_xb0, DIR=1: read g_xb1
__global__ __launch_bounds__(256) void k_gather(){
    const ushort* xb = DIR ? g_xb1 : g_xb0;
    const int wv = threadIdx.x >> 6, lane = threadIdx.x & 63;
    const int half = lane >> 5, sub = lane & 31;       // half 0: even edges, half 1: odd edges
    const int d = blockIdx.x*4 + wv;
    int b = g_off[d], e = g_off[d+1];
    int deg = e - b;
    int sv = (lane < deg) ? g_srcarr[b+lane] : 0;
    float a0=0.f,a1=0.f,a2=0.f,a3=0.f,a4=0.f,a5=0.f,a6=0.f,a7=0.f;
    // paired iterations: lanes 0-31 take edge i, lanes 32-63 take edge i+1; each lane loads 8 cols (16B)
    int i = 0;
    for (; i+1 < deg && i+1 < 64; i += 2){
        int myEdge = i + half;
        int s = __shfl(sv, myEdge);
        ushort8 v = *(const ushort8*)(xb + (size_t)s*NHH + 8*sub);
        a0 += bu2f(v[0]); a1 += bu2f(v[1]); a2 += bu2f(v[2]); a3 += bu2f(v[3]);
        a4 += bu2f(v[4]); a5 += bu2f(v[5]); a6 += bu2f(v[6]); a7 += bu2f(v[7]);
    }
    // tail: remaining edges (odd-deg last edge, or deg>64 spill) processed by half 0 only
    for (; i < deg; i++){
        int s = (i < 64) ? __shfl(sv, i) : g_srcarr[b+i];
        if (half == 0){
            ushort8 v = *(const ushort8*)(xb + (size_t)s*NHH + 8*sub);
            a0 += bu2f(v[0]); a1 += bu2f(v[1]); a2 += bu2f(v[2]); a3 += bu2f(v[3]);
            a4 += bu2f(v[4]); a5 += bu2f(v[5]); a6 += bu2f(v[6]); a7 += bu2f(v[7]);
        }
    }
    // combine even-half + odd-half partials (cols 8*sub..8*sub+7): final = even + odd
    float b0=__shfl_xor(a0,32), b1=__shfl_xor(a1,32), b2=__shfl_xor(a2,32), b3=__shfl_xor(a3,32);
    float b4=__shfl_xor(a4,32), b5=__shfl_xor(a5,32), b6=__shfl_xor(a6,32), b7=__shfl_xor(a7,32);
    if (half == 0){
        ushort8 o;
        o[0]=f2bu(a0+b0); o[1]=f2bu(a1+b1); o[2]=f2bu(a2+b2); o[3]=f2bu(a3+b3);
        o[4]=f2bu(a4+b4); o[5]=f2bu(a5+b5); o[6]=f2bu(a6+b6); o[7]=f2bu(a7+b7);
        *(ushort8*)(g_hf + (size_t)d*HFB + 8*sub) = o;   // [256:288] tail pre-baked by k_sfg0
    }
}

// ---------------- recurrent MFMA GEMM ----------------
template<int DIR>   // DIR=0: residual/in g_x0 -> out g_x1(+xb1); DIR=1: reverse
__global__ __launch_bounds__(256) void k_gemmr(
    int loff, const float* __restrict__ bias, int relu_res)
{
    const float* xnin = DIR ? g_x1 : g_x0;
    float*       xout = DIR ? g_x0 : g_x1;
    ushort*      xbout= DIR ? g_xb0 : g_xb1;
    const int d0 = blockIdx.x*16;
    const int w = threadIdx.x>>6, l = threadIdx.x&63;
    const ushort* arow = g_hf + (size_t)(d0 + (l&15))*HFB + 8*(l>>4);
    f32x4 acc0={0,0,0,0}, acc1={0,0,0,0}, acc2={0,0,0,0}, acc3={0,0,0,0};
    for (int kt=0; kt<9; kt++){
        bf16x8 a = *(const bf16x8*)(arow + kt*32);
        const ushort* bp = g_wpk + ((size_t)(((loff+kt)*16 + w*4)*64 + l))*8;
        bf16x8 b0 = *(const bf16x8*)(bp);
        bf16x8 b1 = *(const bf16x8*)(bp + 64*8);
        bf16x8 b2 = *(const bf16x8*)(bp + 2*64*8);
        bf16x8 b3 = *(const bf16x8*)(bp + 3*64*8);
        acc0 = __builtin_amdgcn_mfma_f32_16x16x32_bf16(a, b0, acc0, 0,0,0);
        acc1 = __builtin_amdgcn_mfma_f32_16x16x32_bf16(a, b1, acc1, 0,0,0);
        acc2 = __builtin_amdgcn_mfma_f32_16x16x32_bf16(a, b2, acc2, 0,0,0);
        acc3 = __builtin_amdgcn_mfma_f32_16x16x32_bf16(a, b3, acc3, 0,0,0);
    }
    const int rb = (l>>4)*4, cb = w*64 + (l&15);
    #define EPIR(ACC, NT) { \
        int col = cb + (NT)*16; float bb = bias[col]; \
        _Pragma("unroll") for (int r=0;r<4;r++){ \
            int d = d0 + rb + r; \
            float val = ACC[r]*g_inorm[d] + bb; \
            if (relu_res){ \
                float y = xnin[(size_t)d*NHH+col] + fmaxf(val,0.f); \
                float yn = y*g_onorm[d]; \
                xout [(size_t)d*NHH+col] = yn; \
                xbout[(size_t)d*NHH+col] = f2bu(yn); \
            } else { \
                xout[(size_t)d*NHH+col] = val; \
            } } }
    EPIR(acc0,0) EPIR(acc1,1) EPIR(acc2,2) EPIR(acc3,3)
    #undef EPIR
}

// ---------------- fused pooling + heads (block g pools its own group, 4x25 partial order) ----------------
__global__ __launch_bounds__(256) void k_heads(
    const int* __restrict__ cgroups,
    const float* __restrict__ sW, const float* __restrict__ sb,
    const float* __restrict__ nW, const float* __restrict__ nb, float* __restrict__ out)
{
    __shared__ float red[256];
    __shared__ float z[9];
    int g=blockIdx.x, t=threadIdx.x;
    float sp[4];
    #pragma unroll
    for (int p=0;p<4;p++){
        float s=0.f;
        for (int i=p*25;i<p*25+25;i++){
            int idx=clampi(cgroups[g*GSZ+i],0,NCN-1);
            s += g_x1[(size_t)idx*NHH+t];
        }
        sp[p]=s;
    }
    float e = ((sp[0]+sp[1])+sp[2])+sp[3];
    for (int j=0;j<9;j++){
        float w = (j==0) ? nW[t] : sW[t*TGG+(j-1)];
        red[t]=e*w; __syncthreads();
        for (int s=128;s>0;s>>=1){ if (t<s) red[t]+=red[t+s]; __syncthreads(); }
        if (t==0) z[j]=red[0];
        __syncthreads();
    }
    if (t==0){
        float z0 = z[0] + nb[0];
        float lsig = fminf(z0,0.f) - log1pf(expf(-fabsf(z0)));
        out[g*9+0]=lsig;
        float zz[8]; float m=-1e30f;
        for (int j=0;j<8;j++){ zz[j]=z[j+1]+sb[j]; m=fmaxf(m,zz[j]); }
        float s=0.f;
        for (int j=0;j<8;j++) s+=expf(zz[j]-m);
        float lse=m+logf(s);
        for (int j=0;j<8;j++) out[g*9+1+j]=zz[j]-lse;
    }
}

extern "C" void kernel_launch(void* const* d_in, const int* in_sizes, int n_in,
                              void* d_out, int out_size, void* d_ws, size_t ws_size,
                              hipStream_t stream) {
    const int expect[24] = {
        NCN*CFF, ECN*CEE, NTT*TFF, ETT*TEE, 256*OPEE,
        (TFF+TEE)*NHH, NHH, 3*(NHH+TEE)*NHH, 3*NHH,
        (CFF+OPEE+TGG*NHH+CEE)*NHH, NHH, 5*(NHH+CEE)*NHH, 5*NHH,
        NHH*TGG, TGG, NHH, 1,
        NCN, ECN, ECN, ETT, ETT, GCN*GSZ, TGG*2
    };
    if (n_in < 24){
        k_badsize<<<(out_size+255)/256,256,0,stream>>>((float*)d_out, out_size, 2.0e6f);
        return;
    }
    for (int i=0;i<24;i++){
        if (in_sizes[i] != expect[i]){
            k_badsize<<<(out_size+255)/256,256,0,stream>>>((float*)d_out, out_size, 1.0e6f+(float)i);
            return;
        }
    }

    const float* cfeats = (const float*)d_in[0];
    const float* cef    = (const float*)d_in[1];
    const float* tfeats = (const float*)d_in[2];
    const float* tef    = (const float*)d_in[3];
    const float* opemb  = (const float*)d_in[4];
    const float* tW0    = (const float*)d_in[5];
    const float* tb0    = (const float*)d_in[6];
    const float* tWr    = (const float*)d_in[7];
    const float* tbr    = (const float*)d_in[8];
    const float* cW0    = (const float*)d_in[9];
    const float* cb0    = (const float*)d_in[10];
    const float* cWr    = (const float*)d_in[11];
    const float* cbr    = (const float*)d_in[12];
    const float* sW     = (const float*)d_in[13];
    const float* sb     = (const float*)d_in[14];
    const float* nW     = (const float*)d_in[15];
    const float* nb     = (const float*)d_in[16];
    const int* ctypes   = (const int*)d_in[17];
    const int* c_src    = (const int*)d_in[18];
    const int* c_dst    = (const int*)d_in[19];
    const int* t_src    = (const int*)d_in[20];
    const int* t_dst    = (const int*)d_in[21];
    const int* cgroups  = (const int*)d_in[22];
    const int* tgroups  = (const int*)d_in[23];

    k_prep0  <<<248, 256, 0, stream>>>(cWr, cW0, tfeats, tef, tW0, tb0, t_src, t_dst);
    k_degrees<<<EBLK+16, 256, 0, stream>>>(c_src, c_dst, tef, tWr, tbr, t_src, t_dst);
    k_scan   <<<17, 1024, 0, stream>>>(tef, tWr, tbr, t_src, t_dst);
    k_scatter<<<EBLK+16, 256, 0, stream>>>(c_dst, tef, tWr, tbr, t_src, t_dst);
    k_sfg0   <<<2508, 256, 0, stream>>>(c_src, cef, ctypes, cfeats, opemb, cW0, tgroups);
    k_gemm0  <<<NCN/16, 256, 0, stream>>>(cb0);

    // 5 recurrent layers: x0 -> x1 -> x0 -> x1 -> x0 -> x1 (final raw f32 in g_x1)
    k_gather<0><<<NCN/4, 256, 0, stream>>>();
    k_gemmr <0><<<NCN/16, 256, 0, stream>>>(0*9, cbr + 0*NHH, 1);
    k_gather<1><<<NCN/4, 256, 0, stream>>>();
    k_gemmr <1><<<NCN/16, 256, 0, stream>>>(1*9, cbr + 1*NHH, 1);
    k_gather<0><<<NCN/4, 256, 0, stream>>>();
    k_gemmr <0><<<NCN/16, 256, 0, stream>>>(2*9, cbr + 2*NHH, 1);
    k_gather<1><<<NCN/4, 256, 0, stream>>>();
    k_gemmr <1><<<NCN/16, 256, 0, stream>>>(3*9, cbr + 3*NHH, 1);
    k_gather<0><<<NCN/4, 256, 0, stream>>>();
    k_gemmr <0><<<NCN/16, 256, 0, stream>>>(4*9, cbr + 4*NHH, 0);

    k_heads<<<GCN, 256, 0, stream>>>(cgroups, sW, sb, nW, nb, (float*)d_out);
}

// Round 20
// 237.754 us; speedup vs baseline: 1.4455x; 1.0482x over previous
//
#include <hip/hip_runtime.h>
#include <hip/hip_bf16.h>

#define NCN 10000   // computation nodes
#define ECN 120000  // computation edges
#define NHH 256     // hidden
#define CEE 16      // cedge feat dim
#define GCN 100     // cgroups
#define GSZ 100     // nodes per cgroup
#define NTT 16      // topo nodes
#define ETT 64      // topo edges
#define TGG 8       // tgroups
#define OPEE 4
#define CFF 64
#define TFF 32
#define TEE 16
#define HFW 272     // true K (256 + 16 eagg)
#define HFB 288     // padded K for MFMA (9*32)
#define HFB0 96     // layer-0 padded K (3*32)
#define NPACKR (5*9*16*64)   // 46080 packwr items -> 180 blocks
#define NPACK0 (3*16*64)     // 3072 packw0 items  -> 12 blocks
#define EBLK ((ECN+255)/256) // 469
#define TSPAN ((NHH+TEE)*NHH)

typedef __attribute__((ext_vector_type(8))) short bf16x8;
typedef __attribute__((ext_vector_type(4))) float f32x4;
typedef __attribute__((ext_vector_type(8))) ushort ushort8;

// ---------- static device scratch (no d_ws dependency) ----------
__device__ int    g_indeg[NCN];
__device__ int    g_outdeg[NCN];
__device__ int    g_cursor[NCN];
__device__ int    g_off[NCN+1];
__device__ int    g_eid[ECN];
__device__ int    g_srcarr[ECN];
__device__ float  g_onorm[NCN];
__device__ float  g_inorm[NCN];
__device__ float  g_son[NCN];
__device__ float  g_tx0[NTT*NHH];
__device__ float  g_tx1[NTT*NHH];
__device__ float  g_v0p[TGG*NHH];
__device__ float  g_x0[(size_t)NCN*NHH];     // f32 xn state (normalized) / final raw
__device__ float  g_x1[(size_t)NCN*NHH];
__device__ ushort g_xb0[(size_t)NCN*NHH];    // bf16 mirror of xn (gather input)
__device__ ushort g_xb1[(size_t)NCN*NHH];
__device__ ushort g_hf [(size_t)NCN*HFB];    // bf16 gathered rows; [256:272]=eagg, [272:288]=0
__device__ ushort g_hf0[(size_t)NCN*HFB0];   // bf16 layer-0 rows
__device__ ushort g_wpk [NPACKR*8];          // cWr packed into B-fragment order
__device__ ushort g_wpk0[NPACK0*8];          // cW0 packed (k=68..71 zeroed; v0 term in f32 epilogue)

__device__ __forceinline__ int clampi(int v,int lo,int hi){ return v<lo?lo:(v>hi?hi:v); }
__device__ __forceinline__ ushort f2bu(float f){ __hip_bfloat16 h=__float2bfloat16(f); return *reinterpret_cast<ushort*>(&h); }
__device__ __forceinline__ float  bu2f(ushort u){ return __uint_as_float(((unsigned)u)<<16); }

__global__ __launch_bounds__(256) void k_badsize(float* out, int n, float code){
    int i = blockIdx.x*256 + threadIdx.x;
    if (i < n) out[i] = code;
}

// ---------------- topo GNN device bodies (16 blocks each, guarded for >=256-thread blocks) ----------------
__device__ __forceinline__ void topo_edges_norms(
    const int* __restrict__ t_src, const int* __restrict__ t_dst,
    int* ssrc, int* sdst, int* sdeg, float* onrm, float* inrm, int t)
{
    if (t < 2*NTT) sdeg[t]=0;
    __syncthreads();
    if (t < ETT){
        int s=clampi(t_src[t],0,NTT-1), d=clampi(t_dst[t],0,NTT-1);
        ssrc[t]=s; sdst[t]=d;
        atomicAdd(&sdeg[s],1); atomicAdd(&sdeg[NTT+d],1);
    }
    __syncthreads();
    if (t < NTT){
        onrm[t]=rsqrtf((float)max(sdeg[t],1));
        inrm[t]=rsqrtf((float)max(sdeg[NTT+t],1));
    }
    __syncthreads();
}

__device__ __forceinline__ void topo_l0_body(
    const float* __restrict__ tfeats, const float* __restrict__ tef,
    const float* __restrict__ tW0, const float* __restrict__ tb0,
    const int* __restrict__ t_src, const int* __restrict__ t_dst, int d, int t)
{
    __shared__ float h0[48];
    __shared__ int ssrc[ETT], sdst[ETT], sdeg[2*NTT];
    __shared__ float onrm[NTT], inrm[NTT];
    topo_edges_norms(t_src, t_dst, ssrc, sdst, sdeg, onrm, inrm, t);
    if (t < 48){
        float acc=0.f;
        for (int e=0;e<ETT;e++){
            if (sdst[e]==d){
                int s=ssrc[e];
                float v = (t<TFF) ? tfeats[s*TFF+t]*onrm[s] : tef[e*TEE+(t-TFF)];
                acc += fmaxf(v,0.f);
            }
        }
        h0[t]=acc;
    }
    __syncthreads();
    if (t < NHH){
        float acc=0.f;
        for (int k=0;k<48;k++) acc += h0[k]*tW0[k*NHH+t];
        g_tx0[d*NHH+t] = fmaxf(acc*inrm[d]+tb0[t], 0.f);
    }
}

__device__ __forceinline__ void topo_lr_body(
    const float* __restrict__ tef,
    const float* __restrict__ W, const float* __restrict__ bias,
    const int* __restrict__ t_src, const int* __restrict__ t_dst,
    const float* __restrict__ xin, float* __restrict__ xout,
    int relu_res, int d, int t)
{
    __shared__ float h[NHH+TEE];
    __shared__ int ssrc[ETT], sdst[ETT], sdeg[2*NTT];
    __shared__ float onrm[NTT], inrm[NTT];
    topo_edges_norms(t_src, t_dst, ssrc, sdst, sdeg, onrm, inrm, t);
    if (t < NHH){
        float a0=0.f, a1=0.f;
        for (int e=0;e<ETT;e++){
            if (sdst[e]==d){
                a0 += xin[ssrc[e]*NHH+t]*onrm[ssrc[e]];
                if (t<TEE) a1 += tef[e*TEE+t];
            }
        }
        h[t]=a0;
        if (t<TEE) h[NHH+t]=a1;
    }
    __syncthreads();
    if (t < NHH){
        float acc=0.f;
        for (int k=0;k<NHH+TEE;k++) acc += h[k]*W[(size_t)k*NHH+t];
        float val = acc*inrm[d] + bias[t];
        xout[d*NHH+t] = relu_res ? (xin[d*NHH+t]*onrm[d] + fmaxf(val,0.f)) : val;
    }
}

// -------- prep0: packwr (0..179) | packw0 (180..191) | zero (192..231) | topo-l0 (232..247) --------
__global__ __launch_bounds__(256) void k_prep0(
    const float* __restrict__ cWr, const float* __restrict__ cW0,
    const float* __restrict__ tfeats, const float* __restrict__ tef,
    const float* __restrict__ tW0, const float* __restrict__ tb0,
    const int* __restrict__ t_src, const int* __restrict__ t_dst)
{
    int bid = blockIdx.x, t = threadIdx.x;
    if (bid < 180){
        int i = bid*256 + t;
        if (i >= NPACKR) return;
        int lane = i&63, u = i>>6;
        int ntg = u&15; u >>= 4;
        int kt = u%9, l = u/9;
        int col = ntg*16 + (lane&15);
        int kb = kt*32 + 8*(lane>>4);
        #pragma unroll
        for (int j=0;j<8;j++){
            int k = kb + j;
            float v = (k < HFW) ? cWr[(size_t)l*HFW*NHH + (size_t)k*NHH + col] : 0.f;
            g_wpk[(size_t)i*8 + j] = f2bu(v);
        }
    } else if (bid < 192){
        int i = (bid-180)*256 + t;
        if (i >= NPACK0) return;
        int lane = i&63, u = i>>6;
        int ntg = u&15, kt = u>>4;
        int col = ntg*16 + (lane&15);
        int kb = kt*32 + 8*(lane>>4);
        #pragma unroll
        for (int j=0;j<8;j++){
            int k = kb + j;
            float v = 0.f;
            if (k < CFF+OPEE)            v = cW0[(size_t)k*NHH+col];
            else if (k >= 72 && k < 88)  v = cW0[(size_t)(CFF+OPEE+TGG*NHH + (k-72))*NHH + col];
            g_wpk0[(size_t)i*8 + j] = f2bu(v);
        }
    } else if (bid < 232){
        int i = (bid-192)*256 + t;
        if (i < NCN){ g_indeg[i]=0; g_outdeg[i]=0; g_cursor[i]=0; }
    } else {
        topo_l0_body(tfeats, tef, tW0, tb0, t_src, t_dst, bid-232, t);
    }
}

// -------- degrees (0..EBLK-1) | topo-lr0 (EBLK..EBLK+15) --------
__global__ __launch_bounds__(256) void k_degrees(
    const int* __restrict__ src, const int* __restrict__ dst,
    const float* __restrict__ tef, const float* __restrict__ tWr, const float* __restrict__ tbr,
    const int* __restrict__ t_src, const int* __restrict__ t_dst)
{
    int bid = blockIdx.x;
    if (bid < EBLK){
        int e = bid*256 + threadIdx.x;
        if (e < ECN){
            atomicAdd(&g_outdeg[clampi(src[e],0,NCN-1)],1);
            atomicAdd(&g_indeg [clampi(dst[e],0,NCN-1)],1);
        }
    } else {
        topo_lr_body(tef, tWr, tbr, t_src, t_dst, g_tx0, g_tx1, 1, bid-EBLK, threadIdx.x);
    }
}

// -------- scan+norms (block 0) | topo-lr1 (blocks 1..16) --------
__global__ __launch_bounds__(1024) void k_scan(
    const float* __restrict__ tef, const float* __restrict__ tWr, const float* __restrict__ tbr,
    const int* __restrict__ t_src, const int* __restrict__ t_dst)
{
    if (blockIdx.x == 0){
        __shared__ int cs[1024];
        const int CH = (NCN + 1023)/1024;
        int t = threadIdx.x;
        int base = t*CH;
        for (int j=0;j<CH;j++){
            int idx = base+j;
            if (idx < NCN){
                g_onorm[idx] = rsqrtf((float)max(g_outdeg[idx],1));
                g_inorm[idx] = rsqrtf((float)max(g_indeg[idx],1));
            }
        }
        int s = 0;
        for (int j=0;j<CH;j++){ int idx=base+j; if (idx<NCN) s += g_indeg[idx]; }
        cs[t] = s; __syncthreads();
        for (int ofs=1; ofs<1024; ofs<<=1){
            int v = (t>=ofs) ? cs[t-ofs] : 0;
            __syncthreads();
            cs[t] += v;
            __syncthreads();
        }
        int run = (t==0) ? 0 : cs[t-1];
        for (int j=0;j<CH;j++){
            int idx = base+j;
            if (idx <= NCN) g_off[idx] = run;
            if (idx < NCN) run += g_indeg[idx];
        }
    } else {
        topo_lr_body(tef, tWr + (size_t)1*TSPAN, tbr + NHH, t_src, t_dst,
                     g_tx1, g_tx0, 1, blockIdx.x-1, threadIdx.x);
    }
}

// -------- scatter (0..EBLK-1) | topo-lr2 final (EBLK..EBLK+15) --------
__global__ __launch_bounds__(256) void k_scatter(
    const int* __restrict__ dst,
    const float* __restrict__ tef, const float* __restrict__ tWr, const float* __restrict__ tbr,
    const int* __restrict__ t_src, const int* __restrict__ t_dst)
{
    int bid = blockIdx.x;
    if (bid < EBLK){
        int e = bid*256 + threadIdx.x;
        if (e < ECN){
            int d = clampi(dst[e],0,NCN-1);
            int pos = g_off[d] + atomicAdd(&g_cursor[d],1);
            g_eid[clampi(pos,0,ECN-1)] = e;
        }
    } else {
        topo_lr_body(tef, tWr + (size_t)2*TSPAN, tbr + 2*NHH, t_src, t_dst,
                     g_tx0, g_tx1, 0, bid-EBLK, threadIdx.x);
    }
}

// -------- fused sortfill + eagg(4-edge) + gather0(2-edge) (0..2499) | v0 partials (2500..2507) --------
// NOTE: all __shfl calls execute UNIFORMLY (outside divergent guards) — ds_bpermute
// returns 0 when reading from an EXEC-disabled lane (round-19 bug).
__global__ __launch_bounds__(256) void k_sfg0(
    const int* __restrict__ c_src, const float* __restrict__ ef,
    const int* __restrict__ ctypes, const float* __restrict__ cfeats,
    const float* __restrict__ opemb,
    const float* __restrict__ cW0, const int* __restrict__ tgroups)
{
    int bid = blockIdx.x;
    if (bid >= 2500){
        __shared__ float srt[NHH];
        int b = bid-2500, c = threadIdx.x;
        int i0=clampi(tgroups[b*2+0],0,NTT-1), i1=clampi(tgroups[b*2+1],0,NTT-1);
        srt[c]=fmaxf(g_tx1[i0*NHH+c]+g_tx1[i1*NHH+c],0.f);
        __syncthreads();
        const float* Wm = cW0 + (size_t)(CFF+OPEE + b*NHH)*NHH;
        float acc=0.f;
        for (int j=0;j<NHH;j++) acc += srt[j]*Wm[(size_t)j*NHH+c];
        g_v0p[b*NHH+c]=acc;
        return;
    }
    const int wv = threadIdx.x >> 6, lane = threadIdx.x & 63;
    const int d = bid*4 + wv;
    int b = clampi(g_off[d],0,ECN), e = clampi(g_off[d+1],b,ECN);
    int deg = e - b;
    if (deg <= 64){
        int v = (lane < deg) ? g_eid[b+lane] : 0x7fffffff;
        #pragma unroll
        for (int k=2;k<=64;k<<=1){
            #pragma unroll
            for (int j=k>>1;j>0;j>>=1){
                int p = __shfl_xor(v, j, 64);
                bool takeMin = ((lane & j)==0) == ((lane & k)==0);
                v = takeMin ? min(v,p) : max(v,p);
            }
        }
        int s = 0; float onv = 0.f; int ctv = 0;
        if (lane < deg){
            g_eid[b+lane] = v;
            s = clampi(c_src[clampi(v,0,ECN-1)],0,NCN-1);
            g_srcarr[b+lane] = s;
            onv = g_onorm[s]; ctv = clampi(ctypes[s],0,255);
        }
        // ---- eagg: 4 edges/iter (group grp=lane>>4 takes edge i+grp, f=lane&15 covers 16 cols) ----
        {
            const int grp = lane>>4, f = lane&15;
            float se=0.f, ser=0.f;
            int i = 0;
            for (; i+3 < deg; i += 4){
                int ei = __shfl(v, i+grp);                      // uniform
                float val = ef[(size_t)clampi(ei,0,ECN-1)*CEE + f];
                se += val; ser += fmaxf(val,0.f);
            }
            for (; i < deg; i++){
                int ei = __shfl(v, i);                          // uniform (hoisted out of guard)
                if (grp == 0){
                    float val = ef[(size_t)clampi(ei,0,ECN-1)*CEE + f];
                    se += val; ser += fmaxf(val,0.f);
                }
            }
            se  += __shfl_xor(se,16);  ser += __shfl_xor(ser,16);   // (g0+g1) | (g2+g3)
            se  += __shfl_xor(se,32);  ser += __shfl_xor(ser,32);   // total
            if (lane < CEE){
                g_hf[(size_t)d*HFB + NHH + lane]      = f2bu(se);
                g_hf[(size_t)d*HFB + NHH + 16 + lane] = 0;
                g_hf0[(size_t)d*HFB0 + 72 + lane]     = f2bu(ser);
            }
        }
        // ---- gather0: 2 edges/iter (half=lane>>5 takes edge i+half, float2 = cols 2*sub..2*sub+1) ----
        {
            const int half = lane>>5, sub = lane&31;
            float c0=0.f, c1=0.f, aop=0.f, aon=0.f;
            int i = 0;
            for (; i+1 < deg; i += 2){
                int eIdx = i + half;
                int si = __shfl(s, eIdx); float on = __shfl(onv, eIdx); int ct = __shfl(ctv, eIdx);
                float2 cf = *(const float2*)(cfeats + (size_t)si*CFF + 2*sub);
                c0 += fmaxf(cf.x,0.f)*on;
                c1 += fmaxf(cf.y,0.f)*on;
                if (sub < OPEE) aop += fmaxf(opemb[ct*OPEE+sub],0.f)*on;
                aon += on;
            }
            for (; i < deg; i++){
                int si = __shfl(s, i); float on = __shfl(onv, i); int ct = __shfl(ctv, i);  // uniform
                if (half == 0){
                    float2 cf = *(const float2*)(cfeats + (size_t)si*CFF + 2*sub);
                    c0 += fmaxf(cf.x,0.f)*on;
                    c1 += fmaxf(cf.y,0.f)*on;
                    if (sub < OPEE) aop += fmaxf(opemb[ct*OPEE+sub],0.f)*on;
                    aon += on;
                }
            }
            c0 += __shfl_xor(c0,32); c1 += __shfl_xor(c1,32);
            aop += __shfl_xor(aop,32); aon += __shfl_xor(aon,32);
            if (half == 0){
                ushort* row = g_hf0 + (size_t)d*HFB0;
                row[2*sub]   = f2bu(c0);
                row[2*sub+1] = f2bu(c1);
                if (sub < OPEE)            row[CFF+sub] = f2bu(aop);
                if (sub >= 4 && sub < 8)   row[64+sub] = 0;      // cols 68..71
                if (sub >= 8 && sub < 16)  row[80+sub] = 0;      // cols 88..95
                if (sub == 16)             g_son[d] = aon;
            }
        }
    } else if (lane == 0){
        for (int i=b+1;i<e;i++){
            int key = g_eid[i]; int j = i-1;
            while (j>=b && g_eid[j]>key){ g_eid[j+1]=g_eid[j]; j--; }
            g_eid[j+1] = key;
        }
        for (int i=b;i<e;i++) g_srcarr[i] = clampi(c_src[clampi(g_eid[i],0,ECN-1)],0,NCN-1);
        ushort* row = g_hf0 + (size_t)d*HFB0;
        for (int f=0;f<CEE;f++){
            float se=0.f, ser=0.f;
            for (int i=b;i<e;i++){
                float val = ef[(size_t)clampi(g_eid[i],0,ECN-1)*CEE + f];
                se += val; ser += fmaxf(val,0.f);
            }
            g_hf[(size_t)d*HFB + NHH + f]      = f2bu(se);
            g_hf[(size_t)d*HFB + NHH + 16 + f] = 0;
            row[72+f] = f2bu(ser);
        }
        for (int c=0;c<CFF;c++){
            float a=0.f;
            for (int i=b;i<e;i++){ int si=g_srcarr[i]; a += fmaxf(cfeats[(size_t)si*CFF+c],0.f)*g_onorm[si]; }
            row[c] = f2bu(a);
        }
        for (int c=0;c<OPEE;c++){
            float a=0.f;
            for (int i=b;i<e;i++){ int si=g_srcarr[i]; int ct=clampi(ctypes[si],0,255); a += fmaxf(opemb[ct*OPEE+c],0.f)*g_onorm[si]; }
            row[CFF+c] = f2bu(a);
        }
        float aon=0.f;
        for (int i=b;i<e;i++) aon += g_onorm[g_srcarr[i]];
        g_son[d]=aon;
        for (int c=68;c<72;c++) row[c]=0;
        for (int c=88;c<96;c++) row[c]=0;
    }
}

// ---------------- layer-0 MFMA GEMM: writes f32 xn0 + bf16 mirror (v0p summed inline) ----------------
__global__ __launch_bounds__(256) void k_gemm0(const float* __restrict__ cb0){
    const int d0 = blockIdx.x*16;
    const int w = threadIdx.x>>6, l = threadIdx.x&63;
    const ushort* arow = g_hf0 + (size_t)(d0 + (l&15))*HFB0 + 8*(l>>4);
    f32x4 acc0={0,0,0,0}, acc1={0,0,0,0}, acc2={0,0,0,0}, acc3={0,0,0,0};
    for (int kt=0; kt<3; kt++){
        bf16x8 a = *(const bf16x8*)(arow + kt*32);
        const ushort* bp = g_wpk0 + ((size_t)((kt*16 + w*4)*64 + l))*8;
        bf16x8 b0 = *(const bf16x8*)(bp);
        bf16x8 b1 = *(const bf16x8*)(bp + 64*8);
        bf16x8 b2 = *(const bf16x8*)(bp + 2*64*8);
        bf16x8 b3 = *(const bf16x8*)(bp + 3*64*8);
        acc0 = __builtin_amdgcn_mfma_f32_16x16x32_bf16(a, b0, acc0, 0,0,0);
        acc1 = __builtin_amdgcn_mfma_f32_16x16x32_bf16(a, b1, acc1, 0,0,0);
        acc2 = __builtin_amdgcn_mfma_f32_16x16x32_bf16(a, b2, acc2, 0,0,0);
        acc3 = __builtin_amdgcn_mfma_f32_16x16x32_bf16(a, b3, acc3, 0,0,0);
    }
    const int rb = (l>>4)*4, cb = w*64 + (l&15);
    #define EPI0(ACC, NT) { \
        int col = cb + (NT)*16; float bb = cb0[col]; \
        float v0c = 0.f; \
        _Pragma("unroll") for (int b8=0;b8<TGG;b8++) v0c += g_v0p[b8*NHH+col]; \
        _Pragma("unroll") for (int r=0;r<4;r++){ \
            int d = d0 + rb + r; \
            float val = (ACC[r] + g_son[d]*v0c)*g_inorm[d] + bb; \
            float xn = fmaxf(val,0.f)*g_onorm[d]; \
            g_x0 [(size_t)d*NHH+col] = xn; \
            g_xb0[(size_t)d*NHH+col] = f2bu(xn); } }
    EPI0(acc0,0) EPI0(acc1,1) EPI0(acc2,2) EPI0(acc3,3)
    #undef EPI0
}

// ------- recurrent gather: wave per node, 2 edges/iter via 16B loads, shfl-xor combine -------
template<int DIR>   // DIR=0: read g_xb0, DIR=1: read g_xb1
__global__ __launch_bounds__(256) void k_gather(){
    const ushort* xb = DIR ? g_xb1 : g_xb0;
    const int wv = threadIdx.x >> 6, lane = threadIdx.x & 63;
    const int half = lane >> 5, sub = lane & 31;       // half 0: even edges, half 1: odd edges
    const int d = blockIdx.x*4 + wv;
    int b = g_off[d], e = g_off[d+1];
    int deg = e - b;
    int sv = (lane < deg) ? g_srcarr[b+lane] : 0;
    float a0=0.f,a1=0.f,a2=0.f,a3=0.f,a4=0.f,a5=0.f,a6=0.f,a7=0.f;
    int i = 0;
    for (; i+1 < deg && i+1 < 64; i += 2){
        int myEdge = i + half;
        int s = __shfl(sv, myEdge);
        ushort8 v = *(const ushort8*)(xb + (size_t)s*NHH + 8*sub);
        a0 += bu2f(v[0]); a1 += bu2f(v[1]); a2 += bu2f(v[2]); a3 += bu2f(v[3]);
        a4 += bu2f(v[4]); a5 += bu2f(v[5]); a6 += bu2f(v[6]); a7 += bu2f(v[7]);
    }
    for (; i < deg; i++){
        int s = (i < 64) ? __shfl(sv, i) : g_srcarr[b+i];   // uniform shfl
        if (half == 0){
            ushort8 v = *(const ushort8*)(xb + (size_t)s*NHH + 8*sub);
            a0 += bu2f(v[0]); a1 += bu2f(v[1]); a2 += bu2f(v[2]); a3 += bu2f(v[3]);
            a4 += bu2f(v[4]); a5 += bu2f(v[5]); a6 += bu2f(v[6]); a7 += bu2f(v[7]);
        }
    }
    float b0=__shfl_xor(a0,32), b1=__shfl_xor(a1,32), b2=__shfl_xor(a2,32), b3=__shfl_xor(a3,32);
    float b4=__shfl_xor(a4,32), b5=__shfl_xor(a5,32), b6=__shfl_xor(a6,32), b7=__shfl_xor(a7,32);
    if (half == 0){
        ushort8 o;
        o[0]=f2bu(a0+b0); o[1]=f2bu(a1+b1); o[2]=f2bu(a2+b2); o[3]=f2bu(a3+b3);
        o[4]=f2bu(a4+b4); o[5]=f2bu(a5+b5); o[6]=f2bu(a6+b6); o[7]=f2bu(a7+b7);
        *(ushort8*)(g_hf + (size_t)d*HFB + 8*sub) = o;   // [256:288] tail pre-baked by k_sfg0
    }
}

// ---------------- recurrent MFMA GEMM ----------------
template<int DIR>   // DIR=0: residual/in g_x0 -> out g_x1(+xb1); DIR=1: reverse
__global__ __launch_bounds__(256) void k_gemmr(
    int loff, const float* __restrict__ bias, int relu_res)
{
    const float* xnin = DIR ? g_x1 : g_x0;
    float*       xout = DIR ? g_x0 : g_x1;
    ushort*      xbout= DIR ? g_xb0 : g_xb1;
    const int d0 = blockIdx.x*16;
    const int w = threadIdx.x>>6, l = threadIdx.x&63;
    const ushort* arow = g_hf + (size_t)(d0 + (l&15))*HFB + 8*(l>>4);
    f32x4 acc0={0,0,0,0}, acc1={0,0,0,0}, acc2={0,0,0,0}, acc3={0,0,0,0};
    for (int kt=0; kt<9; kt++){
        bf16x8 a = *(const bf16x8*)(arow + kt*32);
        const ushort* bp = g_wpk + ((size_t)(((loff+kt)*16 + w*4)*64 + l))*8;
        bf16x8 b0 = *(const bf16x8*)(bp);
        bf16x8 b1 = *(const bf16x8*)(bp + 64*8);
        bf16x8 b2 = *(const bf16x8*)(bp + 2*64*8);
        bf16x8 b3 = *(const bf16x8*)(bp + 3*64*8);
        acc0 = __builtin_amdgcn_mfma_f32_16x16x32_bf16(a, b0, acc0, 0,0,0);
        acc1 = __builtin_amdgcn_mfma_f32_16x16x32_bf16(a, b1, acc1, 0,0,0);
        acc2 = __builtin_amdgcn_mfma_f32_16x16x32_bf16(a, b2, acc2, 0,0,0);
        acc3 = __builtin_amdgcn_mfma_f32_16x16x32_bf16(a, b3, acc3, 0,0,0);
    }
    const int rb = (l>>4)*4, cb = w*64 + (l&15);
    #define EPIR(ACC, NT) { \
        int col = cb + (NT)*16; float bb = bias[col]; \
        _Pragma("unroll") for (int r=0;r<4;r++){ \
            int d = d0 + rb + r; \
            float val = ACC[r]*g_inorm[d] + bb; \
            if (relu_res){ \
                float y = xnin[(size_t)d*NHH+col] + fmaxf(val,0.f); \
                float yn = y*g_onorm[d]; \
                xout [(size_t)d*NHH+col] = yn; \
                xbout[(size_t)d*NHH+col] = f2bu(yn); \
            } else { \
                xout[(size_t)d*NHH+col] = val; \
            } } }
    EPIR(acc0,0) EPIR(acc1,1) EPIR(acc2,2) EPIR(acc3,3)
    #undef EPIR
}

// ---------------- fused pooling + heads (block g pools its own group, 4x25 partial order) ----------------
__global__ __launch_bounds__(256) void k_heads(
    const int* __restrict__ cgroups,
    const float* __restrict__ sW, const float* __restrict__ sb,
    const float* __restrict__ nW, const float* __restrict__ nb, float* __restrict__ out)
{
    __shared__ float red[256];
    __shared__ float z[9];
    int g=blockIdx.x, t=threadIdx.x;
    float sp[4];
    #pragma unroll
    for (int p=0;p<4;p++){
        float s=0.f;
        for (int i=p*25;i<p*25+25;i++){
            int idx=clampi(cgroups[g*GSZ+i],0,NCN-1);
            s += g_x1[(size_t)idx*NHH+t];
        }
        sp[p]=s;
    }
    float e = ((sp[0]+sp[1])+sp[2])+sp[3];
    for (int j=0;j<9;j++){
        float w = (j==0) ? nW[t] : sW[t*TGG+(j-1)];
        red[t]=e*w; __syncthreads();
        for (int s=128;s>0;s>>=1){ if (t<s) red[t]+=red[t+s]; __syncthreads(); }
        if (t==0) z[j]=red[0];
        __syncthreads();
    }
    if (t==0){
        float z0 = z[0] + nb[0];
        float lsig = fminf(z0,0.f) - log1pf(expf(-fabsf(z0)));
        out[g*9+0]=lsig;
        float zz[8]; float m=-1e30f;
        for (int j=0;j<8;j++){ zz[j]=z[j+1]+sb[j]; m=fmaxf(m,zz[j]); }
        float s=0.f;
        for (int j=0;j<8;j++) s+=expf(zz[j]-m);
        float lse=m+logf(s);
        for (int j=0;j<8;j++) out[g*9+1+j]=zz[j]-lse;
    }
}

extern "C" void kernel_launch(void* const* d_in, const int* in_sizes, int n_in,
                              void* d_out, int out_size, void* d_ws, size_t ws_size,
                              hipStream_t stream) {
    const int expect[24] = {
        NCN*CFF, ECN*CEE, NTT*TFF, ETT*TEE, 256*OPEE,
        (TFF+TEE)*NHH, NHH, 3*(NHH+TEE)*NHH, 3*NHH,
        (CFF+OPEE+TGG*NHH+CEE)*NHH, NHH, 5*(NHH+CEE)*NHH, 5*NHH,
        NHH*TGG, TGG, NHH, 1,
        NCN, ECN, ECN, ETT, ETT, GCN*GSZ, TGG*2
    };
    if (n_in < 24){
        k_badsize<<<(out_size+255)/256,256,0,stream>>>((float*)d_out, out_size, 2.0e6f);
        return;
    }
    for (int i=0;i<24;i++){
        if (in_sizes[i] != expect[i]){
            k_badsize<<<(out_size+255)/256,256,0,stream>>>((float*)d_out, out_size, 1.0e6f+(float)i);
            return;
        }
    }

    const float* cfeats = (const float*)d_in[0];
    const float* cef    = (const float*)d_in[1];
    const float* tfeats = (const float*)d_in[2];
    const float* tef    = (const float*)d_in[3];
    const float* opemb  = (const float*)d_in[4];
    const float* tW0    = (const float*)d_in[5];
    const float* tb0    = (const float*)d_in[6];
    const float* tWr    = (const float*)d_in[7];
    const float* tbr    = (const float*)d_in[8];
    const float* cW0    = (const float*)d_in[9];
    const float* cb0    = (const float*)d_in[10];
    const float* cWr    = (const float*)d_in[11];
    const float* cbr    = (const float*)d_in[12];
    const float* sW     = (const float*)d_in[13];
    const float* sb     = (const float*)d_in[14];
    const float* nW     = (const float*)d_in[15];
    const float* nb     = (const float*)d_in[16];
    const int* ctypes   = (const int*)d_in[17];
    const int* c_src    = (const int*)d_in[18];
    const int* c_dst    = (const int*)d_in[19];
    const int* t_src    = (const int*)d_in[20];
    const int* t_dst    = (const int*)d_in[21];
    const int* cgroups  = (const int*)d_in[22];
    const int* tgroups  = (const int*)d_in[23];

    k_prep0  <<<248, 256, 0, stream>>>(cWr, cW0, tfeats, tef, tW0, tb0, t_src, t_dst);
    k_degrees<<<EBLK+16, 256, 0, stream>>>(c_src, c_dst, tef, tWr, tbr, t_src, t_dst);
    k_scan   <<<17, 1024, 0, stream>>>(tef, tWr, tbr, t_src, t_dst);
    k_scatter<<<EBLK+16, 256, 0, stream>>>(c_dst, tef, tWr, tbr, t_src, t_dst);
    k_sfg0   <<<2508, 256, 0, stream>>>(c_src, cef, ctypes, cfeats, opemb, cW0, tgroups);
    k_gemm0  <<<NCN/16, 256, 0, stream>>>(cb0);

    // 5 recurrent layers: x0 -> x1 -> x0 -> x1 -> x0 -> x1 (final raw f32 in g_x1)
    k_gather<0><<<NCN/4, 256, 0, stream>>>();
    k_gemmr <0><<<NCN/16, 256, 0, stream>>>(0*9, cbr + 0*NHH, 1);
    k_gather<1><<<NCN/4, 256, 0, stream>>>();
    k_gemmr <1><<<NCN/16, 256, 0, stream>>>(1*9, cbr + 1*NHH, 1);
    k_gather<0><<<NCN/4, 256, 0, stream>>>();
    k_gemmr <0><<<NCN/16, 256, 0, stream>>>(2*9, cbr + 2*NHH, 1);
    k_gather<1><<<NCN/4, 256, 0, stream>>>();
    k_gemmr <1><<<NCN/16, 256, 0, stream>>>(3*9, cbr + 3*NHH, 1);
    k_gather<0><<<NCN/4, 256, 0, stream>>>();
    k_gemmr <0><<<NCN/16, 256, 0, stream>>>(4*9, cbr + 4*NHH, 0);

    k_heads<<<GCN, 256, 0, stream>>>(cgroups, sW, sb, nW, nb, (float*)d_out);
}